// Round 13
// baseline (943.166 us; speedup 1.0000x reference)
//
#include <hip/hip_runtime.h>

typedef __attribute__((ext_vector_type(8))) short bf16x8;
typedef __attribute__((ext_vector_type(4))) float f32x4;
typedef __attribute__((ext_vector_type(16))) float f32x16;

// ---- bf16 helpers ----
__device__ __forceinline__ unsigned bfr16(float x) {            // RNE fp32->bf16 bits
    unsigned u = __float_as_uint(x);
    return (u + 0x7fffu + ((u >> 16) & 1u)) >> 16;
}
__device__ __forceinline__ float lo16f(unsigned u) { return __uint_as_float(u << 16); }
__device__ __forceinline__ float hi16f(unsigned u) { return __uint_as_float(u & 0xffff0000u); }

union U8 { bf16x8 v; unsigned u[4]; };

// fragment from 8 fp32 (round each to bf16)
__device__ __forceinline__ void frag_from_f32(const float* fp, bf16x8& hi) {
    float4 f0 = *(const float4*)fp;
    float4 f1 = *(const float4*)(fp + 4);
    float fv[8] = {f0.x, f0.y, f0.z, f0.w, f1.x, f1.y, f1.z, f1.w};
    U8 H;
    #pragma unroll
    for (int p = 0; p < 4; p++)
        H.u[p] = bfr16(fv[2 * p]) | (bfr16(fv[2 * p + 1]) << 16);
    hi = H.v;
}

// stage one prepped weight matrix (32 KB bf16) into LDS with 512 threads
__device__ __forceinline__ void stage_w512(unsigned short* sm, const unsigned short* Wp, int t) {
    const uint4* src = (const uint4*)Wp;
    uint4* dst = (uint4*)sm;
    #pragma unroll
    for (int p = 0; p < 4; p++) dst[t + p * 512] = src[t + p * 512];
}

__device__ __forceinline__ bf16x8 wfrag_lds(const unsigned short* sm, int f, int lane) {
    return *(const bf16x8*)(sm + f * 512 + lane * 8);
}

// ---- 16x16 path slot map (GCN layers): chan(nt, rho=4g+r) = 32*(nt>>1)+8*g+4*(nt&1)+r
// ---- 32x32 path slot map (MLP): D slot (n, reg, h=lane>>5) <-> true channel
//      c = kt*16 + h*8 + j  with kt = 2n + (reg>>3), j = reg&7
//      => next-layer B-frag(kt) = acc[kt>>1][(kt&1)*8 + j] (register relabel)

// 32x32 layer transition: y(kt) fragment from acc half + bias (+relu), bf16
__device__ __forceinline__ bf16x8 trans32(const f32x16& A, int sb, float4 bva, float4 bvb) {
    float v0 = fmaxf(A[sb + 0] + bva.x, 0.f);
    float v1 = fmaxf(A[sb + 1] + bva.y, 0.f);
    float v2 = fmaxf(A[sb + 2] + bva.z, 0.f);
    float v3 = fmaxf(A[sb + 3] + bva.w, 0.f);
    float v4 = fmaxf(A[sb + 4] + bvb.x, 0.f);
    float v5 = fmaxf(A[sb + 5] + bvb.y, 0.f);
    float v6 = fmaxf(A[sb + 6] + bvb.z, 0.f);
    float v7 = fmaxf(A[sb + 7] + bvb.w, 0.f);
    U8 H;
    H.u[0] = bfr16(v0) | (bfr16(v1) << 16);
    H.u[1] = bfr16(v2) | (bfr16(v3) << 16);
    H.u[2] = bfr16(v4) | (bfr16(v5) << 16);
    H.u[3] = bfr16(v6) | (bfr16(v7) << 16);
    return H.v;
}

// ---------------- CSR build + degree ordering ----------------

__global__ void zero2_k(int* __restrict__ a, int* __restrict__ b, int n) {
    int i = blockIdx.x * blockDim.x + threadIdx.x;
    if (i < n) { a[i] = 0; b[i] = 0; }
}

__global__ void hist_k(const int* __restrict__ dst, int* __restrict__ deg, int E) {
    int e = blockIdx.x * blockDim.x + threadIdx.x;
    if (e < E) atomicAdd(&deg[dst[e]], 1);
}

__global__ void scan1_k(const int* __restrict__ deg, int* __restrict__ rowptr,
                        int* __restrict__ bsum, float* __restrict__ dinv, int n) {
    __shared__ int s[256];
    int tid = threadIdx.x;
    int i = blockIdx.x * 256 + tid;
    int v = (i < n) ? deg[i] : 0;
    s[tid] = v;
    __syncthreads();
    #pragma unroll
    for (int off = 1; off < 256; off <<= 1) {
        int t = (tid >= off) ? s[tid - off] : 0;
        __syncthreads();
        s[tid] += t;
        __syncthreads();
    }
    if (i < n) {
        rowptr[i] = s[tid] - v;
        dinv[i] = rsqrtf((float)(v + 1));
    }
    if (tid == 255) bsum[blockIdx.x] = s[255];
}

__global__ void scan2_k(int* __restrict__ bsum, int nb) {
    __shared__ int s[512];
    int tid = threadIdx.x;
    int v = (tid < nb) ? bsum[tid] : 0;
    s[tid] = v;
    __syncthreads();
    #pragma unroll
    for (int off = 1; off < 512; off <<= 1) {
        int t = (tid >= off) ? s[tid - off] : 0;
        __syncthreads();
        s[tid] += t;
        __syncthreads();
    }
    if (tid < nb) bsum[tid] = s[tid] - v;
}

__global__ void scan3_k(int* __restrict__ rowptr, const int* __restrict__ bsum, int n) {
    int i = blockIdx.x * blockDim.x + threadIdx.x;
    if (i < n) rowptr[i] += bsum[i >> 8];
}

__global__ void place_k(const int* __restrict__ src, const int* __restrict__ dst,
                        const int* __restrict__ rowptr, int* __restrict__ cursor,
                        int* __restrict__ csr, int E) {
    int e = blockIdx.x * blockDim.x + threadIdx.x;
    if (e < E) {
        int d = dst[e];
        int pos = rowptr[d] + atomicAdd(&cursor[d], 1);
        csr[pos] = src[e];
    }
}

// degree bucketing: order[] = node ids sorted by (clamped) degree
__global__ void dhist_k(const int* __restrict__ deg, int* __restrict__ dbin, int n) {
    int i = blockIdx.x * blockDim.x + threadIdx.x;
    if (i < n) atomicAdd(&dbin[min(deg[i], 127)], 1);
}

__global__ void dscan_k(const int* __restrict__ dbin, int* __restrict__ dcur) {
    __shared__ int s[128];
    int tid = threadIdx.x;  // 128 threads
    int v = dbin[tid];
    s[tid] = v;
    __syncthreads();
    #pragma unroll
    for (int off = 1; off < 128; off <<= 1) {
        int t = (tid >= off) ? s[tid - off] : 0;
        __syncthreads();
        s[tid] += t;
        __syncthreads();
    }
    dcur[tid] = s[tid] - v;   // exclusive offsets
}

__global__ void dplace_k(const int* __restrict__ deg, int* __restrict__ dcur,
                         int* __restrict__ order, int n) {
    int i = blockIdx.x * blockDim.x + threadIdx.x;
    if (i < n) {
        int pos = atomicAdd(&dcur[min(deg[i], 127)], 1);
        order[pos] = i;
    }
}

// ---- weight prep (bf16 single plane, 16384 u16 per matrix).
// y=0,1 -> 16x16 A-frag format (GCN). y=2..5 -> 32x32 A-frag format (MLP).
__global__ void wprep6_k(const float* __restrict__ s0, const float* __restrict__ s1,
                         const float* __restrict__ s2, const float* __restrict__ s3,
                         const float* __restrict__ s4, const float* __restrict__ s5,
                         unsigned short* __restrict__ dstBase) {
    const float* W;
    switch (blockIdx.y) {
        case 0: W = s0; break; case 1: W = s1; break; case 2: W = s2; break;
        case 3: W = s3; break; case 4: W = s4; break; default: W = s5; break;
    }
    unsigned short* out = dstBase + (size_t)blockIdx.y * 16384;
    int idx = blockIdx.x * 256 + threadIdx.x;
    if (idx >= 16384) return;
    int k = idx >> 7, c = idx & 127;
    unsigned hr = bfr16(W[k * 128 + c]);
    int pos;
    if (blockIdx.y < 2) {
        int kt = k >> 5, gk = (k >> 3) & 3, j = k & 7;
        int nt = ((c >> 5) << 1) | ((c >> 2) & 1);
        int rho = (((c >> 3) & 3) << 2) | (c & 3);
        int lane = (gk << 4) | rho;
        pos = (kt * 8 + nt) * 512 + lane * 8 + j;
    } else {
        int kk = k >> 4, gk = (k >> 3) & 1, jj = k & 7;
        int ktc = c >> 4, hc = (c >> 3) & 1, jc = c & 7;
        int n = ktc >> 1;
        int reg = ((ktc & 1) << 3) | jc;
        int m = (reg & 3) + 8 * (reg >> 2) + 4 * hc;
        int lane = (gk << 5) | m;
        pos = (kk * 4 + n) * 512 + lane * 8 + jj;
    }
    out[pos] = (unsigned short)hr;
}

// ---- gather aggregate (degree-ordered): out[i] = relu(bias + dinv[i]*(hp[i] + sum_in hp[s])).
// hp = bf16 plane. 4 nodes/wave via order[] (equal-degree co-scheduling); 8-deep unroll.
__global__ __launch_bounds__(256)
void gather4_k(const unsigned short* __restrict__ hp, const float* __restrict__ dinv,
               const int* __restrict__ rowptr, const int* __restrict__ deg,
               const int* __restrict__ csr, const int* __restrict__ order,
               const float* __restrict__ bias, unsigned short* __restrict__ out, int N)
{
    int tid = threadIdx.x;
    int lane = tid & 63;
    int grp = lane >> 4, cl = lane & 15;
    int idx = blockIdx.x * 16 + (tid >> 6) * 4 + grp;
    if (idx >= N) return;
    int i = order[idx];
    int c8 = cl * 8;
    uint4 p = *(const uint4*)(hp + (size_t)i * 128 + c8);
    float a0 = lo16f(p.x), a1 = hi16f(p.x), a2 = lo16f(p.y), a3 = hi16f(p.y);
    float a4 = lo16f(p.z), a5 = hi16f(p.z), a6 = lo16f(p.w), a7 = hi16f(p.w);
    int beg = rowptr[i], dg = deg[i];
    int j = 0;
    for (; j + 7 < dg; j += 8) {
        uint4 q[8];
        #pragma unroll
        for (int u = 0; u < 8; u++) {
            int su = csr[beg + j + u];
            q[u] = *(const uint4*)(hp + (size_t)su * 128 + c8);
        }
        #pragma unroll
        for (int u = 0; u < 8; u++) {
            a0 += lo16f(q[u].x); a1 += hi16f(q[u].x);
            a2 += lo16f(q[u].y); a3 += hi16f(q[u].y);
            a4 += lo16f(q[u].z); a5 += hi16f(q[u].z);
            a6 += lo16f(q[u].w); a7 += hi16f(q[u].w);
        }
    }
    for (; j + 3 < dg; j += 4) {
        uint4 q[4];
        #pragma unroll
        for (int u = 0; u < 4; u++) {
            int su = csr[beg + j + u];
            q[u] = *(const uint4*)(hp + (size_t)su * 128 + c8);
        }
        #pragma unroll
        for (int u = 0; u < 4; u++) {
            a0 += lo16f(q[u].x); a1 += hi16f(q[u].x);
            a2 += lo16f(q[u].y); a3 += hi16f(q[u].y);
            a4 += lo16f(q[u].z); a5 += hi16f(q[u].z);
            a6 += lo16f(q[u].w); a7 += hi16f(q[u].w);
        }
    }
    for (; j < dg; j++) {
        int s0 = csr[beg + j];
        uint4 q0 = *(const uint4*)(hp + (size_t)s0 * 128 + c8);
        a0 += lo16f(q0.x); a1 += hi16f(q0.x); a2 += lo16f(q0.y); a3 += hi16f(q0.y);
        a4 += lo16f(q0.z); a5 += hi16f(q0.z); a6 += lo16f(q0.w); a7 += hi16f(q0.w);
    }
    float di = dinv[i];
    float4 bv0 = *(const float4*)(bias + c8);
    float4 bv1 = *(const float4*)(bias + c8 + 4);
    uint4 o;
    o.x = bfr16(fmaxf(bv0.x + di * a0, 0.f)) | (bfr16(fmaxf(bv0.y + di * a1, 0.f)) << 16);
    o.y = bfr16(fmaxf(bv0.z + di * a2, 0.f)) | (bfr16(fmaxf(bv0.w + di * a3, 0.f)) << 16);
    o.z = bfr16(fmaxf(bv1.x + di * a4, 0.f)) | (bfr16(fmaxf(bv1.y + di * a5, 0.f)) << 16);
    o.w = bfr16(fmaxf(bv1.z + di * a6, 0.f)) | (bfr16(fmaxf(bv1.w + di * a7, 0.f)) << 16);
    *(uint4*)(out + (size_t)i * 128 + c8) = o;
}

// ---- layer GEMM (16x16 path): Chp = dinv ⊙ (A @ W) as bf16 plane. 1 MFMA/frag. ----
template<int AMODE>   // 0: A fp32 ; 1: A bf16 plane
__global__ __launch_bounds__(512)
void rowgemm_k(const void* __restrict__ Asrc, const unsigned short* __restrict__ Wp,
               const float* __restrict__ rowScale, unsigned short* __restrict__ CoutHi, int M)
{
    __shared__ __align__(16) unsigned short smw[16384];   // 32 KB: one bf16 weight matrix
    const int t = threadIdx.x, lane = t & 63, wave = t >> 6;
    const int base = blockIdx.x * 128 + wave * 16;
    const int s = lane & 15, g = lane >> 4, kg = g * 8;
    const int arow = base + s;
    const int rowc = (arow < M) ? arow : (M - 1);

    stage_w512(smw, Wp, t);

    bf16x8 yh[4];
    #pragma unroll
    for (int kt = 0; kt < 4; kt++) {
        if (AMODE == 1)
            yh[kt] = *(const bf16x8*)((const unsigned short*)Asrc + (size_t)rowc * 128 + kt * 32 + kg);
        else
            frag_from_f32((const float*)Asrc + (size_t)rowc * 128 + kt * 32 + kg, yh[kt]);
    }
    __syncthreads();

    f32x4 acc[8];
    #pragma unroll
    for (int nt = 0; nt < 8; nt++) acc[nt] = (f32x4){0.f, 0.f, 0.f, 0.f};

    #pragma unroll
    for (int kt = 0; kt < 4; kt++) {
        #pragma unroll
        for (int nt = 0; nt < 8; nt++) {
            bf16x8 whi = wfrag_lds(smw, kt * 8 + nt, lane);
            acc[nt] = __builtin_amdgcn_mfma_f32_16x16x32_bf16(whi, yh[kt], acc[nt], 0, 0, 0);
        }
    }

    if (arow < M) {
        float sc = rowScale[arow];
        #pragma unroll
        for (int nt = 0; nt < 8; nt++) {
            int cbase = 32 * (nt >> 1) + 8 * g + 4 * (nt & 1);
            ushort4 o;
            o.x = (unsigned short)bfr16(acc[nt][0] * sc);
            o.y = (unsigned short)bfr16(acc[nt][1] * sc);
            o.z = (unsigned short)bfr16(acc[nt][2] * sc);
            o.w = (unsigned short)bfr16(acc[nt][3] * sc);
            *(ushort4*)(CoutHi + (size_t)arow * 128 + cbase) = o;
        }
    }
}

// ---- fused predict MLP (32x32x16, bf16): gather xi/xj -> y1 -> y2 -> y3 -> dot -> out.
// 32 samples/wave, 8 waves (256 samples/block). TWO weight matrices in LDS at a time:
// stage {W1a,W1b} -> layer 1 ; stage {W2,W3} -> layers 2+3 (no intervening barrier).
// All 16 X-row loads issued before first stage (latency hides under staging).
__global__ __launch_bounds__(512)
void mlp_k(const unsigned short* __restrict__ X, const int* __restrict__ psrc, const int* __restrict__ pdst,
           const unsigned short* __restrict__ W1a, const unsigned short* __restrict__ W1b,
           const float* __restrict__ b1, const unsigned short* __restrict__ W2p,
           const float* __restrict__ b2, const unsigned short* __restrict__ W3p,
           const float* __restrict__ b3, const float* __restrict__ w4,
           const float* __restrict__ b4p, float* __restrict__ out, int M)
{
    __shared__ __align__(16) unsigned short smw[2][16384];   // 64 KB: two weight matrices
    const int t = threadIdx.x, lane = t & 63, wave = t >> 6;
    const int base = blockIdx.x * 256 + wave * 32;
    const int s = lane & 31, h8 = (lane >> 5) * 8;
    const int arow = base + s;
    const int rowc = (arow < M) ? arow : (M - 1);
    const int si = psrc[rowc], sj = pdst[rowc];

    // issue all X loads upfront (hide HBM latency under the 64 KB staging)
    bf16x8 xi[8], xj[8];
    #pragma unroll
    for (int kt = 0; kt < 8; kt++)
        xi[kt] = *(const bf16x8*)(X + (size_t)si * 128 + kt * 16 + h8);
    #pragma unroll
    for (int kt = 0; kt < 8; kt++)
        xj[kt] = *(const bf16x8*)(X + (size_t)sj * 128 + kt * 16 + h8);

    stage_w512(smw[0], W1a, t);
    stage_w512(smw[1], W1b, t);
    __syncthreads();

    // ---- layer 1: acc1 = W1a^T xi + W1b^T xj ----
    f32x16 acc1[4];
    #pragma unroll
    for (int nt = 0; nt < 4; nt++)
        #pragma unroll
        for (int q = 0; q < 16; q++) acc1[nt][q] = 0.f;
    #pragma unroll
    for (int kt = 0; kt < 8; kt++) {
        #pragma unroll
        for (int nt = 0; nt < 4; nt++) {
            bf16x8 wa = wfrag_lds(smw[0], kt * 4 + nt, lane);
            acc1[nt] = __builtin_amdgcn_mfma_f32_32x32x16_bf16(wa, xi[kt], acc1[nt], 0, 0, 0);
            bf16x8 wb = wfrag_lds(smw[1], kt * 4 + nt, lane);
            acc1[nt] = __builtin_amdgcn_mfma_f32_32x32x16_bf16(wb, xj[kt], acc1[nt], 0, 0, 0);
        }
    }
    __syncthreads();

    stage_w512(smw[0], W2p, t);
    stage_w512(smw[1], W3p, t);
    __syncthreads();

    // ---- layer 2 ----
    f32x16 acc2[4];
    #pragma unroll
    for (int nt = 0; nt < 4; nt++)
        #pragma unroll
        for (int q = 0; q < 16; q++) acc2[nt][q] = 0.f;
    #pragma unroll
    for (int kt = 0; kt < 8; kt++) {
        float4 bva = *(const float4*)(b1 + kt * 16 + h8);
        float4 bvb = *(const float4*)(b1 + kt * 16 + h8 + 4);
        bf16x8 yh = trans32(acc1[kt >> 1], (kt & 1) * 8, bva, bvb);
        #pragma unroll
        for (int nt = 0; nt < 4; nt++) {
            bf16x8 whi = wfrag_lds(smw[0], kt * 4 + nt, lane);
            acc2[nt] = __builtin_amdgcn_mfma_f32_32x32x16_bf16(whi, yh, acc2[nt], 0, 0, 0);
        }
    }

    // ---- layer 3 (W3 already staged; no barrier) ----
    f32x16 acc3[4];
    #pragma unroll
    for (int nt = 0; nt < 4; nt++)
        #pragma unroll
        for (int q = 0; q < 16; q++) acc3[nt][q] = 0.f;
    #pragma unroll
    for (int kt = 0; kt < 8; kt++) {
        float4 bva = *(const float4*)(b2 + kt * 16 + h8);
        float4 bvb = *(const float4*)(b2 + kt * 16 + h8 + 4);
        bf16x8 yh = trans32(acc2[kt >> 1], (kt & 1) * 8, bva, bvb);
        #pragma unroll
        for (int nt = 0; nt < 4; nt++) {
            bf16x8 whi = wfrag_lds(smw[1], kt * 4 + nt, lane);
            acc3[nt] = __builtin_amdgcn_mfma_f32_32x32x16_bf16(whi, yh, acc3[nt], 0, 0, 0);
        }
    }

    // ---- final: out = relu( sum_c relu(y3[c]) * w4[c] + b4 ) ----
    float p = 0.f;
    #pragma unroll
    for (int nt = 0; nt < 4; nt++) {
        int c1 = 32 * nt + h8;
        int c2 = 32 * nt + 16 + h8;
        float4 b3a = *(const float4*)(b3 + c1);
        float4 b3b = *(const float4*)(b3 + c1 + 4);
        float4 b3c = *(const float4*)(b3 + c2);
        float4 b3d = *(const float4*)(b3 + c2 + 4);
        float4 w4a = *(const float4*)(w4 + c1);
        float4 w4b = *(const float4*)(w4 + c1 + 4);
        float4 w4c = *(const float4*)(w4 + c2);
        float4 w4d = *(const float4*)(w4 + c2 + 4);
        p += fmaxf(acc3[nt][0]  + b3a.x, 0.f) * w4a.x;
        p += fmaxf(acc3[nt][1]  + b3a.y, 0.f) * w4a.y;
        p += fmaxf(acc3[nt][2]  + b3a.z, 0.f) * w4a.z;
        p += fmaxf(acc3[nt][3]  + b3a.w, 0.f) * w4a.w;
        p += fmaxf(acc3[nt][4]  + b3b.x, 0.f) * w4b.x;
        p += fmaxf(acc3[nt][5]  + b3b.y, 0.f) * w4b.y;
        p += fmaxf(acc3[nt][6]  + b3b.z, 0.f) * w4b.z;
        p += fmaxf(acc3[nt][7]  + b3b.w, 0.f) * w4b.w;
        p += fmaxf(acc3[nt][8]  + b3c.x, 0.f) * w4c.x;
        p += fmaxf(acc3[nt][9]  + b3c.y, 0.f) * w4c.y;
        p += fmaxf(acc3[nt][10] + b3c.z, 0.f) * w4c.z;
        p += fmaxf(acc3[nt][11] + b3c.w, 0.f) * w4c.w;
        p += fmaxf(acc3[nt][12] + b3d.x, 0.f) * w4d.x;
        p += fmaxf(acc3[nt][13] + b3d.y, 0.f) * w4d.y;
        p += fmaxf(acc3[nt][14] + b3d.z, 0.f) * w4d.z;
        p += fmaxf(acc3[nt][15] + b3d.w, 0.f) * w4d.w;
    }
    p += __shfl_xor(p, 32, 64);
    if (lane < 32 && arow < M) out[arow] = fmaxf(p + b4p[0], 0.f);
}

extern "C" void kernel_launch(void* const* d_in, const int* in_sizes, int n_in,
                              void* d_out, int out_size, void* d_ws, size_t ws_size,
                              hipStream_t stream)
{
    const float* x   = (const float*)d_in[0];
    const int*   ei  = (const int*)d_in[2];
    const int*   pei = (const int*)d_in[3];
    const float* W1  = (const float*)d_in[4];
    const float* b1  = (const float*)d_in[5];
    const float* W2  = (const float*)d_in[6];
    const float* b2  = (const float*)d_in[7];
    // d_in[8..11] = edge_mlp weights: dead w.r.t. output, skipped
    const float* pW1 = (const float*)d_in[12];
    const float* pb1 = (const float*)d_in[13];
    const float* pW2 = (const float*)d_in[14];
    const float* pb2 = (const float*)d_in[15];
    const float* pW3 = (const float*)d_in[16];
    const float* pb3 = (const float*)d_in[17];
    const float* pW4 = (const float*)d_in[18];
    const float* pb4 = (const float*)d_in[19];

    const int N  = in_sizes[0] / 128;
    const int E  = in_sizes[2] / 2;
    const int EP = in_sizes[3] / 2;
    const int Npad = (N + 255) & ~255;

    float*          ws     = (float*)d_ws;
    float*          dinv   = ws;                                    // Npad
    unsigned short* hpHi   = (unsigned short*)(ws + Npad);          // N*128 u16 (bf16 plane)
    unsigned short* bufB   = hpHi + (size_t)N * 128;                // N*128 u16 (bf16 plane)
    size_t ioff = (((size_t)(bufB + (size_t)N * 128)) + 255) & ~(size_t)255;
    int*   deg    = (int*)ioff;                                     // Npad
    int*   rowptr = deg + Npad;                                     // Npad
    int*   cursor = rowptr + Npad;                                  // Npad
    int*   order  = cursor + Npad;                                  // Npad
    int*   csr    = order + Npad;                                   // E
    int*   bsum   = csr + E;                                        // 512
    int*   dbin   = bsum + 512;                                     // 128
    int*   dcur   = dbin + 128;                                     // 128
    size_t wpOff = ((size_t)(dcur + 128) + 15) & ~(size_t)15;
    unsigned short* wp = (unsigned short*)wpOff;                    // 6 x 16384 u16
    unsigned short* W1p  = wp;
    unsigned short* W2p  = wp + 16384;
    unsigned short* P1Ap = wp + 2 * 16384;
    unsigned short* P1Bp = wp + 3 * 16384;
    unsigned short* P2p  = wp + 4 * 16384;
    unsigned short* P3p  = wp + 5 * 16384;
    float* out = (float*)d_out;

    const int* esrc = ei;
    const int* edst = ei + E;
    const int* psrc = pei;
    const int* pdst = pei + EP;

    const int nb = (N + 255) / 256;
    const int gN = (N + 255) / 256;
    const int gE = (E + 255) / 256;
    const int gT = (N + 127) / 128;
    const int gP = (EP + 255) / 256;    // 256 samples per block (8 waves x 32)
    const int gG = (N + 15) / 16;

    // ---- CSR build + dinv + degree-ordering ----
    zero2_k<<<gN, 256, 0, stream>>>(deg, cursor, N);
    zero2_k<<<1, 128, 0, stream>>>(dbin, dcur, 128);
    hist_k<<<gE, 256, 0, stream>>>(edst, deg, E);
    scan1_k<<<nb, 256, 0, stream>>>(deg, rowptr, bsum, dinv, N);
    scan2_k<<<1, 512, 0, stream>>>(bsum, nb);
    scan3_k<<<gN, 256, 0, stream>>>(rowptr, bsum, N);
    place_k<<<gE, 256, 0, stream>>>(esrc, edst, rowptr, cursor, csr, E);
    dhist_k<<<gN, 256, 0, stream>>>(deg, dbin, N);
    dscan_k<<<1, 128, 0, stream>>>(dbin, dcur);
    dplace_k<<<gN, 256, 0, stream>>>(deg, dcur, order, N);

    // ---- weight prep (bf16, dual fragment format) ----
    wprep6_k<<<dim3(64, 6), 256, 0, stream>>>(W1, W2, pW1, pW1 + 128 * 128, pW2, pW3, wp);

    // ---- layer 0: hp1 = dinv ⊙ (x@W1) [bf16]; x1r = relu(agg + b1) [bf16] ----
    rowgemm_k<0><<<gT, 512, 0, stream>>>(x, W1p, dinv, hpHi, N);
    gather4_k<<<gG, 256, 0, stream>>>(hpHi, dinv, rowptr, deg, csr, order, b1, bufB, N);

    // ---- layer 1 ----
    rowgemm_k<1><<<gT, 512, 0, stream>>>(bufB, W2p, dinv, hpHi, N);
    gather4_k<<<gG, 256, 0, stream>>>(hpHi, dinv, rowptr, deg, csr, order, b2, bufB, N);

    // ---- fused predict MLP (32x32 bf16, 8 waves, 2-matrix LDS staging) ----
    mlp_k<<<gP, 512, 0, stream>>>(bufB, psrc, pdst, P1Ap, P1Bp, pb1, P2p, pb2, P3p, pb3,
                                  pW4, pb4, out, EP);
}

// Round 14
// 203.135 us; speedup vs baseline: 4.6430x; 4.6430x over previous
//
#include <hip/hip_runtime.h>

typedef __attribute__((ext_vector_type(8))) short bf16x8;
typedef __attribute__((ext_vector_type(4))) float f32x4;
typedef __attribute__((ext_vector_type(16))) float f32x16;

// ---- bf16 helpers ----
__device__ __forceinline__ unsigned bfr16(float x) {            // RNE fp32->bf16 bits
    unsigned u = __float_as_uint(x);
    return (u + 0x7fffu + ((u >> 16) & 1u)) >> 16;
}
__device__ __forceinline__ float lo16f(unsigned u) { return __uint_as_float(u << 16); }
__device__ __forceinline__ float hi16f(unsigned u) { return __uint_as_float(u & 0xffff0000u); }

union U8 { bf16x8 v; unsigned u[4]; };

// fragment from 8 fp32 (round each to bf16)
__device__ __forceinline__ void frag_from_f32(const float* fp, bf16x8& hi) {
    float4 f0 = *(const float4*)fp;
    float4 f1 = *(const float4*)(fp + 4);
    float fv[8] = {f0.x, f0.y, f0.z, f0.w, f1.x, f1.y, f1.z, f1.w};
    U8 H;
    #pragma unroll
    for (int p = 0; p < 4; p++)
        H.u[p] = bfr16(fv[2 * p]) | (bfr16(fv[2 * p + 1]) << 16);
    hi = H.v;
}

// stage one prepped weight matrix (32 KB bf16) into LDS with 512 threads
__device__ __forceinline__ void stage_w512(unsigned short* sm, const unsigned short* Wp, int t) {
    const uint4* src = (const uint4*)Wp;
    uint4* dst = (uint4*)sm;
    #pragma unroll
    for (int p = 0; p < 4; p++) dst[t + p * 512] = src[t + p * 512];
}

__device__ __forceinline__ bf16x8 wfrag_lds(const unsigned short* sm, int f, int lane) {
    return *(const bf16x8*)(sm + f * 512 + lane * 8);
}

// ---- 16x16 path slot map (GCN layers): chan(nt, rho=4g+r) = 32*(nt>>1)+8*g+4*(nt&1)+r
// ---- 32x32 path slot map (MLP): D slot (n, reg, h=lane>>5) <-> true channel
//      c = kt*16 + h*8 + j  with kt = 2n + (reg>>3), j = reg&7
//      => next-layer B-frag(kt) = acc[kt>>1][(kt&1)*8 + j] (register relabel)

// 32x32 layer transition: y(kt) fragment from acc half + bias (+relu), bf16
__device__ __forceinline__ bf16x8 trans32(const f32x16& A, int sb, float4 bva, float4 bvb) {
    float v0 = fmaxf(A[sb + 0] + bva.x, 0.f);
    float v1 = fmaxf(A[sb + 1] + bva.y, 0.f);
    float v2 = fmaxf(A[sb + 2] + bva.z, 0.f);
    float v3 = fmaxf(A[sb + 3] + bva.w, 0.f);
    float v4 = fmaxf(A[sb + 4] + bvb.x, 0.f);
    float v5 = fmaxf(A[sb + 5] + bvb.y, 0.f);
    float v6 = fmaxf(A[sb + 6] + bvb.z, 0.f);
    float v7 = fmaxf(A[sb + 7] + bvb.w, 0.f);
    U8 H;
    H.u[0] = bfr16(v0) | (bfr16(v1) << 16);
    H.u[1] = bfr16(v2) | (bfr16(v3) << 16);
    H.u[2] = bfr16(v4) | (bfr16(v5) << 16);
    H.u[3] = bfr16(v6) | (bfr16(v7) << 16);
    return H.v;
}

// ---------------- CSR build ----------------

__global__ void zero2_k(int* __restrict__ a, int* __restrict__ b, int n) {
    int i = blockIdx.x * blockDim.x + threadIdx.x;
    if (i < n) { a[i] = 0; b[i] = 0; }
}

__global__ void hist_k(const int* __restrict__ dst, int* __restrict__ deg, int E) {
    int e = blockIdx.x * blockDim.x + threadIdx.x;
    if (e < E) atomicAdd(&deg[dst[e]], 1);
}

__global__ void scan1_k(const int* __restrict__ deg, int* __restrict__ rowptr,
                        int* __restrict__ bsum, float* __restrict__ dinv, int n) {
    __shared__ int s[256];
    int tid = threadIdx.x;
    int i = blockIdx.x * 256 + tid;
    int v = (i < n) ? deg[i] : 0;
    s[tid] = v;
    __syncthreads();
    #pragma unroll
    for (int off = 1; off < 256; off <<= 1) {
        int t = (tid >= off) ? s[tid - off] : 0;
        __syncthreads();
        s[tid] += t;
        __syncthreads();
    }
    if (i < n) {
        rowptr[i] = s[tid] - v;
        dinv[i] = rsqrtf((float)(v + 1));
    }
    if (tid == 255) bsum[blockIdx.x] = s[255];
}

__global__ void scan2_k(int* __restrict__ bsum, int nb) {
    __shared__ int s[512];
    int tid = threadIdx.x;
    int v = (tid < nb) ? bsum[tid] : 0;
    s[tid] = v;
    __syncthreads();
    #pragma unroll
    for (int off = 1; off < 512; off <<= 1) {
        int t = (tid >= off) ? s[tid - off] : 0;
        __syncthreads();
        s[tid] += t;
        __syncthreads();
    }
    if (tid < nb) bsum[tid] = s[tid] - v;
}

__global__ void scan3_k(int* __restrict__ rowptr, const int* __restrict__ bsum, int n) {
    int i = blockIdx.x * blockDim.x + threadIdx.x;
    if (i < n) rowptr[i] += bsum[i >> 8];
}

__global__ void place_k(const int* __restrict__ src, const int* __restrict__ dst,
                        const int* __restrict__ rowptr, int* __restrict__ cursor,
                        int* __restrict__ csr, int E) {
    int e = blockIdx.x * blockDim.x + threadIdx.x;
    if (e < E) {
        int d = dst[e];
        int pos = rowptr[d] + atomicAdd(&cursor[d], 1);
        csr[pos] = src[e];
    }
}

// ---- weight prep (bf16 single plane, 16384 u16 per matrix).
// y=0,1 -> 16x16 A-frag format (GCN). y=2..5 -> 32x32 A-frag format (MLP).
__global__ void wprep6_k(const float* __restrict__ s0, const float* __restrict__ s1,
                         const float* __restrict__ s2, const float* __restrict__ s3,
                         const float* __restrict__ s4, const float* __restrict__ s5,
                         unsigned short* __restrict__ dstBase) {
    const float* W;
    switch (blockIdx.y) {
        case 0: W = s0; break; case 1: W = s1; break; case 2: W = s2; break;
        case 3: W = s3; break; case 4: W = s4; break; default: W = s5; break;
    }
    unsigned short* out = dstBase + (size_t)blockIdx.y * 16384;
    int idx = blockIdx.x * 256 + threadIdx.x;
    if (idx >= 16384) return;
    int k = idx >> 7, c = idx & 127;
    unsigned hr = bfr16(W[k * 128 + c]);
    int pos;
    if (blockIdx.y < 2) {
        int kt = k >> 5, gk = (k >> 3) & 3, j = k & 7;
        int nt = ((c >> 5) << 1) | ((c >> 2) & 1);
        int rho = (((c >> 3) & 3) << 2) | (c & 3);
        int lane = (gk << 4) | rho;
        pos = (kt * 8 + nt) * 512 + lane * 8 + j;
    } else {
        int kk = k >> 4, gk = (k >> 3) & 1, jj = k & 7;
        int ktc = c >> 4, hc = (c >> 3) & 1, jc = c & 7;
        int n = ktc >> 1;
        int reg = ((ktc & 1) << 3) | jc;
        int m = (reg & 3) + 8 * (reg >> 2) + 4 * hc;
        int lane = (gk << 5) | m;
        pos = (kk * 4 + n) * 512 + lane * 8 + jj;
    }
    out[pos] = (unsigned short)hr;
}

// ---- gather aggregate: out[i] = relu(bias + dinv[i]*(hp[i] + sum_in hp[s])), bf16 plane.
// hp = bf16 plane (2 B/chan). 4 nodes/wave, 16 lanes x 8 chans; 8-deep unroll.
__global__ __launch_bounds__(256)
void gather4_k(const unsigned short* __restrict__ hp, const float* __restrict__ dinv,
               const int* __restrict__ rowptr, const int* __restrict__ deg,
               const int* __restrict__ csr, const float* __restrict__ bias,
               unsigned short* __restrict__ out, int N)
{
    int tid = threadIdx.x;
    int lane = tid & 63;
    int grp = lane >> 4, cl = lane & 15;
    int i = blockIdx.x * 16 + (tid >> 6) * 4 + grp;
    if (i >= N) return;
    int c8 = cl * 8;
    uint4 p = *(const uint4*)(hp + (size_t)i * 128 + c8);
    float a0 = lo16f(p.x), a1 = hi16f(p.x), a2 = lo16f(p.y), a3 = hi16f(p.y);
    float a4 = lo16f(p.z), a5 = hi16f(p.z), a6 = lo16f(p.w), a7 = hi16f(p.w);
    int beg = rowptr[i], dg = deg[i];
    int j = 0;
    for (; j + 7 < dg; j += 8) {
        uint4 q[8];
        #pragma unroll
        for (int u = 0; u < 8; u++) {
            int su = csr[beg + j + u];
            q[u] = *(const uint4*)(hp + (size_t)su * 128 + c8);
        }
        #pragma unroll
        for (int u = 0; u < 8; u++) {
            a0 += lo16f(q[u].x); a1 += hi16f(q[u].x);
            a2 += lo16f(q[u].y); a3 += hi16f(q[u].y);
            a4 += lo16f(q[u].z); a5 += hi16f(q[u].z);
            a6 += lo16f(q[u].w); a7 += hi16f(q[u].w);
        }
    }
    for (; j + 3 < dg; j += 4) {
        uint4 q[4];
        #pragma unroll
        for (int u = 0; u < 4; u++) {
            int su = csr[beg + j + u];
            q[u] = *(const uint4*)(hp + (size_t)su * 128 + c8);
        }
        #pragma unroll
        for (int u = 0; u < 4; u++) {
            a0 += lo16f(q[u].x); a1 += hi16f(q[u].x);
            a2 += lo16f(q[u].y); a3 += hi16f(q[u].y);
            a4 += lo16f(q[u].z); a5 += hi16f(q[u].z);
            a6 += lo16f(q[u].w); a7 += hi16f(q[u].w);
        }
    }
    for (; j < dg; j++) {
        int s0 = csr[beg + j];
        uint4 q0 = *(const uint4*)(hp + (size_t)s0 * 128 + c8);
        a0 += lo16f(q0.x); a1 += hi16f(q0.x); a2 += lo16f(q0.y); a3 += hi16f(q0.y);
        a4 += lo16f(q0.z); a5 += hi16f(q0.z); a6 += lo16f(q0.w); a7 += hi16f(q0.w);
    }
    float di = dinv[i];
    float4 bv0 = *(const float4*)(bias + c8);
    float4 bv1 = *(const float4*)(bias + c8 + 4);
    uint4 o;
    o.x = bfr16(fmaxf(bv0.x + di * a0, 0.f)) | (bfr16(fmaxf(bv0.y + di * a1, 0.f)) << 16);
    o.y = bfr16(fmaxf(bv0.z + di * a2, 0.f)) | (bfr16(fmaxf(bv0.w + di * a3, 0.f)) << 16);
    o.z = bfr16(fmaxf(bv1.x + di * a4, 0.f)) | (bfr16(fmaxf(bv1.y + di * a5, 0.f)) << 16);
    o.w = bfr16(fmaxf(bv1.z + di * a6, 0.f)) | (bfr16(fmaxf(bv1.w + di * a7, 0.f)) << 16);
    *(uint4*)(out + (size_t)i * 128 + c8) = o;
}

// ---- layer GEMM (16x16 path): Chp = dinv ⊙ (A @ W) as bf16 plane. 1 MFMA/frag. ----
template<int AMODE>   // 0: A fp32 ; 1: A bf16 plane
__global__ __launch_bounds__(512)
void rowgemm_k(const void* __restrict__ Asrc, const unsigned short* __restrict__ Wp,
               const float* __restrict__ rowScale, unsigned short* __restrict__ CoutHi, int M)
{
    __shared__ __align__(16) unsigned short smw[16384];   // 32 KB: one bf16 weight matrix
    const int t = threadIdx.x, lane = t & 63, wave = t >> 6;
    const int base = blockIdx.x * 128 + wave * 16;
    const int s = lane & 15, g = lane >> 4, kg = g * 8;
    const int arow = base + s;
    const int rowc = (arow < M) ? arow : (M - 1);

    stage_w512(smw, Wp, t);

    bf16x8 yh[4];
    #pragma unroll
    for (int kt = 0; kt < 4; kt++) {
        if (AMODE == 1)
            yh[kt] = *(const bf16x8*)((const unsigned short*)Asrc + (size_t)rowc * 128 + kt * 32 + kg);
        else
            frag_from_f32((const float*)Asrc + (size_t)rowc * 128 + kt * 32 + kg, yh[kt]);
    }
    __syncthreads();

    f32x4 acc[8];
    #pragma unroll
    for (int nt = 0; nt < 8; nt++) acc[nt] = (f32x4){0.f, 0.f, 0.f, 0.f};

    #pragma unroll
    for (int kt = 0; kt < 4; kt++) {
        #pragma unroll
        for (int nt = 0; nt < 8; nt++) {
            bf16x8 whi = wfrag_lds(smw, kt * 8 + nt, lane);
            acc[nt] = __builtin_amdgcn_mfma_f32_16x16x32_bf16(whi, yh[kt], acc[nt], 0, 0, 0);
        }
    }

    if (arow < M) {
        float sc = rowScale[arow];
        #pragma unroll
        for (int nt = 0; nt < 8; nt++) {
            int cbase = 32 * (nt >> 1) + 8 * g + 4 * (nt & 1);
            ushort4 o;
            o.x = (unsigned short)bfr16(acc[nt][0] * sc);
            o.y = (unsigned short)bfr16(acc[nt][1] * sc);
            o.z = (unsigned short)bfr16(acc[nt][2] * sc);
            o.w = (unsigned short)bfr16(acc[nt][3] * sc);
            *(ushort4*)(CoutHi + (size_t)arow * 128 + cbase) = o;
        }
    }
}

// ---- fused predict MLP (32x32x16, bf16): gather xi/xj -> y1 -> y2 -> y3 -> dot -> out.
// 32 samples/wave, 8 waves (256 samples/block). TWO weight matrices in LDS at a time:
// stage {W1a,W1b} -> layer 1 ; stage {W2,W3} -> layers 2+3 (no intervening barrier).
// All 16 X-row loads issued before first stage (latency hides under staging).
__global__ __launch_bounds__(512)
void mlp_k(const unsigned short* __restrict__ X, const int* __restrict__ psrc, const int* __restrict__ pdst,
           const unsigned short* __restrict__ W1a, const unsigned short* __restrict__ W1b,
           const float* __restrict__ b1, const unsigned short* __restrict__ W2p,
           const float* __restrict__ b2, const unsigned short* __restrict__ W3p,
           const float* __restrict__ b3, const float* __restrict__ w4,
           const float* __restrict__ b4p, float* __restrict__ out, int M)
{
    __shared__ __align__(16) unsigned short smw[2][16384];   // 64 KB: two weight matrices
    const int t = threadIdx.x, lane = t & 63, wave = t >> 6;
    const int base = blockIdx.x * 256 + wave * 32;
    const int s = lane & 31, h8 = (lane >> 5) * 8;
    const int arow = base + s;
    const int rowc = (arow < M) ? arow : (M - 1);
    const int si = psrc[rowc], sj = pdst[rowc];

    // issue all X loads upfront (hide HBM latency under the 64 KB staging)
    bf16x8 xi[8], xj[8];
    #pragma unroll
    for (int kt = 0; kt < 8; kt++)
        xi[kt] = *(const bf16x8*)(X + (size_t)si * 128 + kt * 16 + h8);
    #pragma unroll
    for (int kt = 0; kt < 8; kt++)
        xj[kt] = *(const bf16x8*)(X + (size_t)sj * 128 + kt * 16 + h8);

    stage_w512(smw[0], W1a, t);
    stage_w512(smw[1], W1b, t);
    __syncthreads();

    // ---- layer 1: acc1 = W1a^T xi + W1b^T xj ----
    f32x16 acc1[4];
    #pragma unroll
    for (int nt = 0; nt < 4; nt++)
        #pragma unroll
        for (int q = 0; q < 16; q++) acc1[nt][q] = 0.f;
    #pragma unroll
    for (int kt = 0; kt < 8; kt++) {
        #pragma unroll
        for (int nt = 0; nt < 4; nt++) {
            bf16x8 wa = wfrag_lds(smw[0], kt * 4 + nt, lane);
            acc1[nt] = __builtin_amdgcn_mfma_f32_32x32x16_bf16(wa, xi[kt], acc1[nt], 0, 0, 0);
            bf16x8 wb = wfrag_lds(smw[1], kt * 4 + nt, lane);
            acc1[nt] = __builtin_amdgcn_mfma_f32_32x32x16_bf16(wb, xj[kt], acc1[nt], 0, 0, 0);
        }
    }
    __syncthreads();

    stage_w512(smw[0], W2p, t);
    stage_w512(smw[1], W3p, t);
    __syncthreads();

    // ---- layer 2 ----
    f32x16 acc2[4];
    #pragma unroll
    for (int nt = 0; nt < 4; nt++)
        #pragma unroll
        for (int q = 0; q < 16; q++) acc2[nt][q] = 0.f;
    #pragma unroll
    for (int kt = 0; kt < 8; kt++) {
        float4 bva = *(const float4*)(b1 + kt * 16 + h8);
        float4 bvb = *(const float4*)(b1 + kt * 16 + h8 + 4);
        bf16x8 yh = trans32(acc1[kt >> 1], (kt & 1) * 8, bva, bvb);
        #pragma unroll
        for (int nt = 0; nt < 4; nt++) {
            bf16x8 whi = wfrag_lds(smw[0], kt * 4 + nt, lane);
            acc2[nt] = __builtin_amdgcn_mfma_f32_32x32x16_bf16(whi, yh, acc2[nt], 0, 0, 0);
        }
    }

    // ---- layer 3 (W3 already staged; no barrier) ----
    f32x16 acc3[4];
    #pragma unroll
    for (int nt = 0; nt < 4; nt++)
        #pragma unroll
        for (int q = 0; q < 16; q++) acc3[nt][q] = 0.f;
    #pragma unroll
    for (int kt = 0; kt < 8; kt++) {
        float4 bva = *(const float4*)(b2 + kt * 16 + h8);
        float4 bvb = *(const float4*)(b2 + kt * 16 + h8 + 4);
        bf16x8 yh = trans32(acc2[kt >> 1], (kt & 1) * 8, bva, bvb);
        #pragma unroll
        for (int nt = 0; nt < 4; nt++) {
            bf16x8 whi = wfrag_lds(smw[1], kt * 4 + nt, lane);
            acc3[nt] = __builtin_amdgcn_mfma_f32_32x32x16_bf16(whi, yh, acc3[nt], 0, 0, 0);
        }
    }

    // ---- final: out = relu( sum_c relu(y3[c]) * w4[c] + b4 ) ----
    float p = 0.f;
    #pragma unroll
    for (int nt = 0; nt < 4; nt++) {
        int c1 = 32 * nt + h8;
        int c2 = 32 * nt + 16 + h8;
        float4 b3a = *(const float4*)(b3 + c1);
        float4 b3b = *(const float4*)(b3 + c1 + 4);
        float4 b3c = *(const float4*)(b3 + c2);
        float4 b3d = *(const float4*)(b3 + c2 + 4);
        float4 w4a = *(const float4*)(w4 + c1);
        float4 w4b = *(const float4*)(w4 + c1 + 4);
        float4 w4c = *(const float4*)(w4 + c2);
        float4 w4d = *(const float4*)(w4 + c2 + 4);
        p += fmaxf(acc3[nt][0]  + b3a.x, 0.f) * w4a.x;
        p += fmaxf(acc3[nt][1]  + b3a.y, 0.f) * w4a.y;
        p += fmaxf(acc3[nt][2]  + b3a.z, 0.f) * w4a.z;
        p += fmaxf(acc3[nt][3]  + b3a.w, 0.f) * w4a.w;
        p += fmaxf(acc3[nt][4]  + b3b.x, 0.f) * w4b.x;
        p += fmaxf(acc3[nt][5]  + b3b.y, 0.f) * w4b.y;
        p += fmaxf(acc3[nt][6]  + b3b.z, 0.f) * w4b.z;
        p += fmaxf(acc3[nt][7]  + b3b.w, 0.f) * w4b.w;
        p += fmaxf(acc3[nt][8]  + b3c.x, 0.f) * w4c.x;
        p += fmaxf(acc3[nt][9]  + b3c.y, 0.f) * w4c.y;
        p += fmaxf(acc3[nt][10] + b3c.z, 0.f) * w4c.z;
        p += fmaxf(acc3[nt][11] + b3c.w, 0.f) * w4c.w;
        p += fmaxf(acc3[nt][12] + b3d.x, 0.f) * w4d.x;
        p += fmaxf(acc3[nt][13] + b3d.y, 0.f) * w4d.y;
        p += fmaxf(acc3[nt][14] + b3d.z, 0.f) * w4d.z;
        p += fmaxf(acc3[nt][15] + b3d.w, 0.f) * w4d.w;
    }
    p += __shfl_xor(p, 32, 64);
    if (lane < 32 && arow < M) out[arow] = fmaxf(p + b4p[0], 0.f);
}

extern "C" void kernel_launch(void* const* d_in, const int* in_sizes, int n_in,
                              void* d_out, int out_size, void* d_ws, size_t ws_size,
                              hipStream_t stream)
{
    const float* x   = (const float*)d_in[0];
    const int*   ei  = (const int*)d_in[2];
    const int*   pei = (const int*)d_in[3];
    const float* W1  = (const float*)d_in[4];
    const float* b1  = (const float*)d_in[5];
    const float* W2  = (const float*)d_in[6];
    const float* b2  = (const float*)d_in[7];
    // d_in[8..11] = edge_mlp weights: dead w.r.t. output, skipped
    const float* pW1 = (const float*)d_in[12];
    const float* pb1 = (const float*)d_in[13];
    const float* pW2 = (const float*)d_in[14];
    const float* pb2 = (const float*)d_in[15];
    const float* pW3 = (const float*)d_in[16];
    const float* pb3 = (const float*)d_in[17];
    const float* pW4 = (const float*)d_in[18];
    const float* pb4 = (const float*)d_in[19];

    const int N  = in_sizes[0] / 128;
    const int E  = in_sizes[2] / 2;
    const int EP = in_sizes[3] / 2;
    const int Npad = (N + 255) & ~255;

    float*          ws     = (float*)d_ws;
    float*          dinv   = ws;                                    // Npad
    unsigned short* hpHi   = (unsigned short*)(ws + Npad);          // N*128 u16 (bf16 plane)
    unsigned short* bufB   = hpHi + (size_t)N * 128;                // N*128 u16 (bf16 plane)
    size_t ioff = (((size_t)(bufB + (size_t)N * 128)) + 255) & ~(size_t)255;
    int*   deg    = (int*)ioff;                                     // Npad
    int*   rowptr = deg + Npad;                                     // Npad
    int*   cursor = rowptr + Npad;                                  // Npad
    int*   csr    = cursor + Npad;                                  // E
    int*   bsum   = csr + E;                                        // 512
    size_t wpOff = ((size_t)(bsum + 512) + 15) & ~(size_t)15;
    unsigned short* wp = (unsigned short*)wpOff;                    // 6 x 16384 u16
    unsigned short* W1p  = wp;
    unsigned short* W2p  = wp + 16384;
    unsigned short* P1Ap = wp + 2 * 16384;
    unsigned short* P1Bp = wp + 3 * 16384;
    unsigned short* P2p  = wp + 4 * 16384;
    unsigned short* P3p  = wp + 5 * 16384;
    float* out = (float*)d_out;

    const int* esrc = ei;
    const int* edst = ei + E;
    const int* psrc = pei;
    const int* pdst = pei + EP;

    const int nb = (N + 255) / 256;
    const int gN = (N + 255) / 256;
    const int gE = (E + 255) / 256;
    const int gT = (N + 127) / 128;
    const int gP = (EP + 255) / 256;    // 256 samples per block (8 waves x 32)
    const int gG = (N + 15) / 16;

    // ---- CSR build + dinv ----
    zero2_k<<<gN, 256, 0, stream>>>(deg, cursor, N);
    hist_k<<<gE, 256, 0, stream>>>(edst, deg, E);
    scan1_k<<<nb, 256, 0, stream>>>(deg, rowptr, bsum, dinv, N);
    scan2_k<<<1, 512, 0, stream>>>(bsum, nb);
    scan3_k<<<gN, 256, 0, stream>>>(rowptr, bsum, N);
    place_k<<<gE, 256, 0, stream>>>(esrc, edst, rowptr, cursor, csr, E);

    // ---- weight prep (bf16, dual fragment format) ----
    wprep6_k<<<dim3(64, 6), 256, 0, stream>>>(W1, W2, pW1, pW1 + 128 * 128, pW2, pW3, wp);

    // ---- layer 0: hp1 = dinv ⊙ (x@W1) [bf16]; x1r = relu(agg + b1) [bf16] ----
    rowgemm_k<0><<<gT, 512, 0, stream>>>(x, W1p, dinv, hpHi, N);
    gather4_k<<<gG, 256, 0, stream>>>(hpHi, dinv, rowptr, deg, csr, b1, bufB, N);

    // ---- layer 1 ----
    rowgemm_k<1><<<gT, 512, 0, stream>>>(bufB, W2p, dinv, hpHi, N);
    gather4_k<<<gG, 256, 0, stream>>>(hpHi, dinv, rowptr, deg, csr, b2, bufB, N);

    // ---- fused predict MLP (32x32 bf16, 8 waves, 2-matrix LDS staging) ----
    mlp_k<<<gP, 512, 0, stream>>>(bufB, psrc, pdst, P1Ap, P1Bp, pb1, P2p, pb2, P3p, pb3,
                                  pW4, pb4, out, EP);
}

// Round 15
// 184.631 us; speedup vs baseline: 5.1084x; 1.1002x over previous
//
#include <hip/hip_runtime.h>

typedef __attribute__((ext_vector_type(8))) short bf16x8;
typedef __attribute__((ext_vector_type(4))) float f32x4;
typedef __attribute__((ext_vector_type(16))) float f32x16;

// ---- bf16 helpers ----
__device__ __forceinline__ unsigned bfr16(float x) {            // RNE fp32->bf16 bits
    unsigned u = __float_as_uint(x);
    return (u + 0x7fffu + ((u >> 16) & 1u)) >> 16;
}
__device__ __forceinline__ float lo16f(unsigned u) { return __uint_as_float(u << 16); }
__device__ __forceinline__ float hi16f(unsigned u) { return __uint_as_float(u & 0xffff0000u); }

union U8 { bf16x8 v; unsigned u[4]; };

// fragment from 8 fp32 (round each to bf16)
__device__ __forceinline__ void frag_from_f32(const float* fp, bf16x8& hi) {
    float4 f0 = *(const float4*)fp;
    float4 f1 = *(const float4*)(fp + 4);
    float fv[8] = {f0.x, f0.y, f0.z, f0.w, f1.x, f1.y, f1.z, f1.w};
    U8 H;
    #pragma unroll
    for (int p = 0; p < 4; p++)
        H.u[p] = bfr16(fv[2 * p]) | (bfr16(fv[2 * p + 1]) << 16);
    hi = H.v;
}

// stage one prepped weight matrix (32 KB bf16) into LDS with 512 threads
__device__ __forceinline__ void stage_w512(unsigned short* sm, const unsigned short* Wp, int t) {
    const uint4* src = (const uint4*)Wp;
    uint4* dst = (uint4*)sm;
    #pragma unroll
    for (int p = 0; p < 4; p++) dst[t + p * 512] = src[t + p * 512];
}

__device__ __forceinline__ bf16x8 wfrag_lds(const unsigned short* sm, int f, int lane) {
    return *(const bf16x8*)(sm + f * 512 + lane * 8);
}

// ---- 16x16 path slot map (GCN layers): chan(nt, rho=4g+r) = 32*(nt>>1)+8*g+4*(nt&1)+r
// ---- 32x32 path slot map (MLP): D slot (n, reg, h=lane>>5) <-> true channel
//      c = kt*16 + h*8 + j  with kt = 2n + (reg>>3), j = reg&7
//      => next-layer B-frag(kt) = acc[kt>>1][(kt&1)*8 + j] (register relabel)

// 32x32 layer transition: y(kt) fragment from acc half + bias (+relu), bf16
__device__ __forceinline__ bf16x8 trans32(const f32x16& A, int sb, float4 bva, float4 bvb) {
    float v0 = fmaxf(A[sb + 0] + bva.x, 0.f);
    float v1 = fmaxf(A[sb + 1] + bva.y, 0.f);
    float v2 = fmaxf(A[sb + 2] + bva.z, 0.f);
    float v3 = fmaxf(A[sb + 3] + bva.w, 0.f);
    float v4 = fmaxf(A[sb + 4] + bvb.x, 0.f);
    float v5 = fmaxf(A[sb + 5] + bvb.y, 0.f);
    float v6 = fmaxf(A[sb + 6] + bvb.z, 0.f);
    float v7 = fmaxf(A[sb + 7] + bvb.w, 0.f);
    U8 H;
    H.u[0] = bfr16(v0) | (bfr16(v1) << 16);
    H.u[1] = bfr16(v2) | (bfr16(v3) << 16);
    H.u[2] = bfr16(v4) | (bfr16(v5) << 16);
    H.u[3] = bfr16(v6) | (bfr16(v7) << 16);
    return H.v;
}

// ---------------- CSR build (rank-from-histogram, atomic-free placement) ----------------

__global__ void zero1_k(int* __restrict__ a, int n) {
    int i = blockIdx.x * blockDim.x + threadIdx.x;
    if (i < n) a[i] = 0;
}

// histogram that keeps the returned rank: deg counts, rank[e] = position within dst bucket
__global__ void hist_k(const int* __restrict__ dst, int* __restrict__ deg,
                       int* __restrict__ rank, int E) {
    int e = blockIdx.x * blockDim.x + threadIdx.x;
    if (e < E) rank[e] = atomicAdd(&deg[dst[e]], 1);
}

__global__ void scan1_k(const int* __restrict__ deg, int* __restrict__ rowptr,
                        int* __restrict__ bsum, float* __restrict__ dinv, int n) {
    __shared__ int s[256];
    int tid = threadIdx.x;
    int i = blockIdx.x * 256 + tid;
    int v = (i < n) ? deg[i] : 0;
    s[tid] = v;
    __syncthreads();
    #pragma unroll
    for (int off = 1; off < 256; off <<= 1) {
        int t = (tid >= off) ? s[tid - off] : 0;
        __syncthreads();
        s[tid] += t;
        __syncthreads();
    }
    if (i < n) {
        rowptr[i] = s[tid] - v;
        dinv[i] = rsqrtf((float)(v + 1));
    }
    if (tid == 255) bsum[blockIdx.x] = s[255];
}

__global__ void scan2_k(int* __restrict__ bsum, int nb) {
    __shared__ int s[512];
    int tid = threadIdx.x;
    int v = (tid < nb) ? bsum[tid] : 0;
    s[tid] = v;
    __syncthreads();
    #pragma unroll
    for (int off = 1; off < 512; off <<= 1) {
        int t = (tid >= off) ? s[tid - off] : 0;
        __syncthreads();
        s[tid] += t;
        __syncthreads();
    }
    if (tid < nb) bsum[tid] = s[tid] - v;
}

__global__ void scan3_k(int* __restrict__ rowptr, const int* __restrict__ bsum, int n) {
    int i = blockIdx.x * blockDim.x + threadIdx.x;
    if (i < n) rowptr[i] += bsum[i >> 8];
}

// atomic-free placement: pos = rowptr[dst] + rank[e]
__global__ void place_k(const int* __restrict__ src, const int* __restrict__ dst,
                        const int* __restrict__ rowptr, const int* __restrict__ rank,
                        int* __restrict__ csr, int E) {
    int e = blockIdx.x * blockDim.x + threadIdx.x;
    if (e < E) {
        int pos = rowptr[dst[e]] + rank[e];
        csr[pos] = src[e];
    }
}

// ---- weight prep (bf16 single plane, 16384 u16 per matrix).
// y=0,1 -> 16x16 A-frag format (GCN). y=2..5 -> 32x32 A-frag format (MLP).
__global__ void wprep6_k(const float* __restrict__ s0, const float* __restrict__ s1,
                         const float* __restrict__ s2, const float* __restrict__ s3,
                         const float* __restrict__ s4, const float* __restrict__ s5,
                         unsigned short* __restrict__ dstBase) {
    const float* W;
    switch (blockIdx.y) {
        case 0: W = s0; break; case 1: W = s1; break; case 2: W = s2; break;
        case 3: W = s3; break; case 4: W = s4; break; default: W = s5; break;
    }
    unsigned short* out = dstBase + (size_t)blockIdx.y * 16384;
    int idx = blockIdx.x * 256 + threadIdx.x;
    if (idx >= 16384) return;
    int k = idx >> 7, c = idx & 127;
    unsigned hr = bfr16(W[k * 128 + c]);
    int pos;
    if (blockIdx.y < 2) {
        int kt = k >> 5, gk = (k >> 3) & 3, j = k & 7;
        int nt = ((c >> 5) << 1) | ((c >> 2) & 1);
        int rho = (((c >> 3) & 3) << 2) | (c & 3);
        int lane = (gk << 4) | rho;
        pos = (kt * 8 + nt) * 512 + lane * 8 + j;
    } else {
        int kk = k >> 4, gk = (k >> 3) & 1, jj = k & 7;
        int ktc = c >> 4, hc = (c >> 3) & 1, jc = c & 7;
        int n = ktc >> 1;
        int reg = ((ktc & 1) << 3) | jc;
        int m = (reg & 3) + 8 * (reg >> 2) + 4 * hc;
        int lane = (gk << 5) | m;
        pos = (kk * 4 + n) * 512 + lane * 8 + jj;
    }
    out[pos] = (unsigned short)hr;
}

// ---- gather aggregate: out[i] = relu(bias + dinv[i]*(hp[i] + sum_in hp[s])), bf16 plane.
// hp = bf16 plane (2 B/chan). 4 nodes/wave, 16 lanes x 8 chans; 8-deep unroll.
__global__ __launch_bounds__(256)
void gather4_k(const unsigned short* __restrict__ hp, const float* __restrict__ dinv,
               const int* __restrict__ rowptr, const int* __restrict__ deg,
               const int* __restrict__ csr, const float* __restrict__ bias,
               unsigned short* __restrict__ out, int N)
{
    int tid = threadIdx.x;
    int lane = tid & 63;
    int grp = lane >> 4, cl = lane & 15;
    int i = blockIdx.x * 16 + (tid >> 6) * 4 + grp;
    if (i >= N) return;
    int c8 = cl * 8;
    uint4 p = *(const uint4*)(hp + (size_t)i * 128 + c8);
    float a0 = lo16f(p.x), a1 = hi16f(p.x), a2 = lo16f(p.y), a3 = hi16f(p.y);
    float a4 = lo16f(p.z), a5 = hi16f(p.z), a6 = lo16f(p.w), a7 = hi16f(p.w);
    int beg = rowptr[i], dg = deg[i];
    int j = 0;
    for (; j + 7 < dg; j += 8) {
        uint4 q[8];
        #pragma unroll
        for (int u = 0; u < 8; u++) {
            int su = csr[beg + j + u];
            q[u] = *(const uint4*)(hp + (size_t)su * 128 + c8);
        }
        #pragma unroll
        for (int u = 0; u < 8; u++) {
            a0 += lo16f(q[u].x); a1 += hi16f(q[u].x);
            a2 += lo16f(q[u].y); a3 += hi16f(q[u].y);
            a4 += lo16f(q[u].z); a5 += hi16f(q[u].z);
            a6 += lo16f(q[u].w); a7 += hi16f(q[u].w);
        }
    }
    for (; j + 3 < dg; j += 4) {
        uint4 q[4];
        #pragma unroll
        for (int u = 0; u < 4; u++) {
            int su = csr[beg + j + u];
            q[u] = *(const uint4*)(hp + (size_t)su * 128 + c8);
        }
        #pragma unroll
        for (int u = 0; u < 4; u++) {
            a0 += lo16f(q[u].x); a1 += hi16f(q[u].x);
            a2 += lo16f(q[u].y); a3 += hi16f(q[u].y);
            a4 += lo16f(q[u].z); a5 += hi16f(q[u].z);
            a6 += lo16f(q[u].w); a7 += hi16f(q[u].w);
        }
    }
    for (; j < dg; j++) {
        int s0 = csr[beg + j];
        uint4 q0 = *(const uint4*)(hp + (size_t)s0 * 128 + c8);
        a0 += lo16f(q0.x); a1 += hi16f(q0.x); a2 += lo16f(q0.y); a3 += hi16f(q0.y);
        a4 += lo16f(q0.z); a5 += hi16f(q0.z); a6 += lo16f(q0.w); a7 += hi16f(q0.w);
    }
    float di = dinv[i];
    float4 bv0 = *(const float4*)(bias + c8);
    float4 bv1 = *(const float4*)(bias + c8 + 4);
    uint4 o;
    o.x = bfr16(fmaxf(bv0.x + di * a0, 0.f)) | (bfr16(fmaxf(bv0.y + di * a1, 0.f)) << 16);
    o.y = bfr16(fmaxf(bv0.z + di * a2, 0.f)) | (bfr16(fmaxf(bv0.w + di * a3, 0.f)) << 16);
    o.z = bfr16(fmaxf(bv1.x + di * a4, 0.f)) | (bfr16(fmaxf(bv1.y + di * a5, 0.f)) << 16);
    o.w = bfr16(fmaxf(bv1.z + di * a6, 0.f)) | (bfr16(fmaxf(bv1.w + di * a7, 0.f)) << 16);
    *(uint4*)(out + (size_t)i * 128 + c8) = o;
}

// ---- layer GEMM (16x16 path): Chp = dinv ⊙ (A @ W) as bf16 plane. 1 MFMA/frag. ----
template<int AMODE>   // 0: A fp32 ; 1: A bf16 plane
__global__ __launch_bounds__(512)
void rowgemm_k(const void* __restrict__ Asrc, const unsigned short* __restrict__ Wp,
               const float* __restrict__ rowScale, unsigned short* __restrict__ CoutHi, int M)
{
    __shared__ __align__(16) unsigned short smw[16384];   // 32 KB: one bf16 weight matrix
    const int t = threadIdx.x, lane = t & 63, wave = t >> 6;
    const int base = blockIdx.x * 128 + wave * 16;
    const int s = lane & 15, g = lane >> 4, kg = g * 8;
    const int arow = base + s;
    const int rowc = (arow < M) ? arow : (M - 1);

    stage_w512(smw, Wp, t);

    bf16x8 yh[4];
    #pragma unroll
    for (int kt = 0; kt < 4; kt++) {
        if (AMODE == 1)
            yh[kt] = *(const bf16x8*)((const unsigned short*)Asrc + (size_t)rowc * 128 + kt * 32 + kg);
        else
            frag_from_f32((const float*)Asrc + (size_t)rowc * 128 + kt * 32 + kg, yh[kt]);
    }
    __syncthreads();

    f32x4 acc[8];
    #pragma unroll
    for (int nt = 0; nt < 8; nt++) acc[nt] = (f32x4){0.f, 0.f, 0.f, 0.f};

    #pragma unroll
    for (int kt = 0; kt < 4; kt++) {
        #pragma unroll
        for (int nt = 0; nt < 8; nt++) {
            bf16x8 whi = wfrag_lds(smw, kt * 8 + nt, lane);
            acc[nt] = __builtin_amdgcn_mfma_f32_16x16x32_bf16(whi, yh[kt], acc[nt], 0, 0, 0);
        }
    }

    if (arow < M) {
        float sc = rowScale[arow];
        #pragma unroll
        for (int nt = 0; nt < 8; nt++) {
            int cbase = 32 * (nt >> 1) + 8 * g + 4 * (nt & 1);
            ushort4 o;
            o.x = (unsigned short)bfr16(acc[nt][0] * sc);
            o.y = (unsigned short)bfr16(acc[nt][1] * sc);
            o.z = (unsigned short)bfr16(acc[nt][2] * sc);
            o.w = (unsigned short)bfr16(acc[nt][3] * sc);
            *(ushort4*)(CoutHi + (size_t)arow * 128 + cbase) = o;
        }
    }
}

// ---- fused predict MLP (32x32x16, bf16): gather xi/xj -> y1 -> y2 -> y3 -> dot -> out.
// 32 samples/wave, 8 waves (256 samples/block). TWO weight matrices in LDS at a time:
// stage {W1a,W1b} -> layer 1 ; stage {W2,W3} -> layers 2+3 (no intervening barrier).
// All 16 X-row loads issued before first stage (latency hides under staging).
__global__ __launch_bounds__(512)
void mlp_k(const unsigned short* __restrict__ X, const int* __restrict__ psrc, const int* __restrict__ pdst,
           const unsigned short* __restrict__ W1a, const unsigned short* __restrict__ W1b,
           const float* __restrict__ b1, const unsigned short* __restrict__ W2p,
           const float* __restrict__ b2, const unsigned short* __restrict__ W3p,
           const float* __restrict__ b3, const float* __restrict__ w4,
           const float* __restrict__ b4p, float* __restrict__ out, int M)
{
    __shared__ __align__(16) unsigned short smw[2][16384];   // 64 KB: two weight matrices
    const int t = threadIdx.x, lane = t & 63, wave = t >> 6;
    const int base = blockIdx.x * 256 + wave * 32;
    const int s = lane & 31, h8 = (lane >> 5) * 8;
    const int arow = base + s;
    const int rowc = (arow < M) ? arow : (M - 1);
    const int si = psrc[rowc], sj = pdst[rowc];

    // issue all X loads upfront (hide HBM latency under the 64 KB staging)
    bf16x8 xi[8], xj[8];
    #pragma unroll
    for (int kt = 0; kt < 8; kt++)
        xi[kt] = *(const bf16x8*)(X + (size_t)si * 128 + kt * 16 + h8);
    #pragma unroll
    for (int kt = 0; kt < 8; kt++)
        xj[kt] = *(const bf16x8*)(X + (size_t)sj * 128 + kt * 16 + h8);

    stage_w512(smw[0], W1a, t);
    stage_w512(smw[1], W1b, t);
    __syncthreads();

    // ---- layer 1: acc1 = W1a^T xi + W1b^T xj ----
    f32x16 acc1[4];
    #pragma unroll
    for (int nt = 0; nt < 4; nt++)
        #pragma unroll
        for (int q = 0; q < 16; q++) acc1[nt][q] = 0.f;
    #pragma unroll
    for (int kt = 0; kt < 8; kt++) {
        #pragma unroll
        for (int nt = 0; nt < 4; nt++) {
            bf16x8 wa = wfrag_lds(smw[0], kt * 4 + nt, lane);
            acc1[nt] = __builtin_amdgcn_mfma_f32_32x32x16_bf16(wa, xi[kt], acc1[nt], 0, 0, 0);
            bf16x8 wb = wfrag_lds(smw[1], kt * 4 + nt, lane);
            acc1[nt] = __builtin_amdgcn_mfma_f32_32x32x16_bf16(wb, xj[kt], acc1[nt], 0, 0, 0);
        }
    }
    __syncthreads();

    stage_w512(smw[0], W2p, t);
    stage_w512(smw[1], W3p, t);
    __syncthreads();

    // ---- layer 2 ----
    f32x16 acc2[4];
    #pragma unroll
    for (int nt = 0; nt < 4; nt++)
        #pragma unroll
        for (int q = 0; q < 16; q++) acc2[nt][q] = 0.f;
    #pragma unroll
    for (int kt = 0; kt < 8; kt++) {
        float4 bva = *(const float4*)(b1 + kt * 16 + h8);
        float4 bvb = *(const float4*)(b1 + kt * 16 + h8 + 4);
        bf16x8 yh = trans32(acc1[kt >> 1], (kt & 1) * 8, bva, bvb);
        #pragma unroll
        for (int nt = 0; nt < 4; nt++) {
            bf16x8 whi = wfrag_lds(smw[0], kt * 4 + nt, lane);
            acc2[nt] = __builtin_amdgcn_mfma_f32_32x32x16_bf16(whi, yh, acc2[nt], 0, 0, 0);
        }
    }

    // ---- layer 3 (W3 already staged; no barrier) ----
    f32x16 acc3[4];
    #pragma unroll
    for (int nt = 0; nt < 4; nt++)
        #pragma unroll
        for (int q = 0; q < 16; q++) acc3[nt][q] = 0.f;
    #pragma unroll
    for (int kt = 0; kt < 8; kt++) {
        float4 bva = *(const float4*)(b2 + kt * 16 + h8);
        float4 bvb = *(const float4*)(b2 + kt * 16 + h8 + 4);
        bf16x8 yh = trans32(acc2[kt >> 1], (kt & 1) * 8, bva, bvb);
        #pragma unroll
        for (int nt = 0; nt < 4; nt++) {
            bf16x8 whi = wfrag_lds(smw[1], kt * 4 + nt, lane);
            acc3[nt] = __builtin_amdgcn_mfma_f32_32x32x16_bf16(whi, yh, acc3[nt], 0, 0, 0);
        }
    }

    // ---- final: out = relu( sum_c relu(y3[c]) * w4[c] + b4 ) ----
    float p = 0.f;
    #pragma unroll
    for (int nt = 0; nt < 4; nt++) {
        int c1 = 32 * nt + h8;
        int c2 = 32 * nt + 16 + h8;
        float4 b3a = *(const float4*)(b3 + c1);
        float4 b3b = *(const float4*)(b3 + c1 + 4);
        float4 b3c = *(const float4*)(b3 + c2);
        float4 b3d = *(const float4*)(b3 + c2 + 4);
        float4 w4a = *(const float4*)(w4 + c1);
        float4 w4b = *(const float4*)(w4 + c1 + 4);
        float4 w4c = *(const float4*)(w4 + c2);
        float4 w4d = *(const float4*)(w4 + c2 + 4);
        p += fmaxf(acc3[nt][0]  + b3a.x, 0.f) * w4a.x;
        p += fmaxf(acc3[nt][1]  + b3a.y, 0.f) * w4a.y;
        p += fmaxf(acc3[nt][2]  + b3a.z, 0.f) * w4a.z;
        p += fmaxf(acc3[nt][3]  + b3a.w, 0.f) * w4a.w;
        p += fmaxf(acc3[nt][4]  + b3b.x, 0.f) * w4b.x;
        p += fmaxf(acc3[nt][5]  + b3b.y, 0.f) * w4b.y;
        p += fmaxf(acc3[nt][6]  + b3b.z, 0.f) * w4b.z;
        p += fmaxf(acc3[nt][7]  + b3b.w, 0.f) * w4b.w;
        p += fmaxf(acc3[nt][8]  + b3c.x, 0.f) * w4c.x;
        p += fmaxf(acc3[nt][9]  + b3c.y, 0.f) * w4c.y;
        p += fmaxf(acc3[nt][10] + b3c.z, 0.f) * w4c.z;
        p += fmaxf(acc3[nt][11] + b3c.w, 0.f) * w4c.w;
        p += fmaxf(acc3[nt][12] + b3d.x, 0.f) * w4d.x;
        p += fmaxf(acc3[nt][13] + b3d.y, 0.f) * w4d.y;
        p += fmaxf(acc3[nt][14] + b3d.z, 0.f) * w4d.z;
        p += fmaxf(acc3[nt][15] + b3d.w, 0.f) * w4d.w;
    }
    p += __shfl_xor(p, 32, 64);
    if (lane < 32 && arow < M) out[arow] = fmaxf(p + b4p[0], 0.f);
}

extern "C" void kernel_launch(void* const* d_in, const int* in_sizes, int n_in,
                              void* d_out, int out_size, void* d_ws, size_t ws_size,
                              hipStream_t stream)
{
    const float* x   = (const float*)d_in[0];
    const int*   ei  = (const int*)d_in[2];
    const int*   pei = (const int*)d_in[3];
    const float* W1  = (const float*)d_in[4];
    const float* b1  = (const float*)d_in[5];
    const float* W2  = (const float*)d_in[6];
    const float* b2  = (const float*)d_in[7];
    // d_in[8..11] = edge_mlp weights: dead w.r.t. output, skipped
    const float* pW1 = (const float*)d_in[12];
    const float* pb1 = (const float*)d_in[13];
    const float* pW2 = (const float*)d_in[14];
    const float* pb2 = (const float*)d_in[15];
    const float* pW3 = (const float*)d_in[16];
    const float* pb3 = (const float*)d_in[17];
    const float* pW4 = (const float*)d_in[18];
    const float* pb4 = (const float*)d_in[19];

    const int N  = in_sizes[0] / 128;
    const int E  = in_sizes[2] / 2;
    const int EP = in_sizes[3] / 2;
    const int Npad = (N + 255) & ~255;

    float*          ws     = (float*)d_ws;
    float*          dinv   = ws;                                    // Npad
    unsigned short* hpHi   = (unsigned short*)(ws + Npad);          // N*128 u16 (bf16 plane)
    unsigned short* bufB   = hpHi + (size_t)N * 128;                // N*128 u16 (bf16 plane)
    size_t ioff = (((size_t)(bufB + (size_t)N * 128)) + 255) & ~(size_t)255;
    int*   deg    = (int*)ioff;                                     // Npad
    int*   rowptr = deg + Npad;                                     // Npad
    int*   rank   = rowptr + Npad;                                  // E
    int*   csr    = rank + E;                                       // E
    int*   bsum   = csr + E;                                        // 512
    size_t wpOff = ((size_t)(bsum + 512) + 15) & ~(size_t)15;
    unsigned short* wp = (unsigned short*)wpOff;                    // 6 x 16384 u16
    unsigned short* W1p  = wp;
    unsigned short* W2p  = wp + 16384;
    unsigned short* P1Ap = wp + 2 * 16384;
    unsigned short* P1Bp = wp + 3 * 16384;
    unsigned short* P2p  = wp + 4 * 16384;
    unsigned short* P3p  = wp + 5 * 16384;
    float* out = (float*)d_out;

    const int* esrc = ei;
    const int* edst = ei + E;
    const int* psrc = pei;
    const int* pdst = pei + EP;

    const int nb = (N + 255) / 256;
    const int gN = (N + 255) / 256;
    const int gE = (E + 255) / 256;
    const int gT = (N + 127) / 128;
    const int gP = (EP + 255) / 256;    // 256 samples per block (8 waves x 32)
    const int gG = (N + 15) / 16;

    // ---- CSR build + dinv (atomic-free placement via rank) ----
    zero1_k<<<gN, 256, 0, stream>>>(deg, N);
    hist_k<<<gE, 256, 0, stream>>>(edst, deg, rank, E);
    scan1_k<<<nb, 256, 0, stream>>>(deg, rowptr, bsum, dinv, N);
    scan2_k<<<1, 512, 0, stream>>>(bsum, nb);
    scan3_k<<<gN, 256, 0, stream>>>(rowptr, bsum, N);
    place_k<<<gE, 256, 0, stream>>>(esrc, edst, rowptr, rank, csr, E);

    // ---- weight prep (bf16, dual fragment format) ----
    wprep6_k<<<dim3(64, 6), 256, 0, stream>>>(W1, W2, pW1, pW1 + 128 * 128, pW2, pW3, wp);

    // ---- layer 0: hp1 = dinv ⊙ (x@W1) [bf16]; x1r = relu(agg + b1) [bf16] ----
    rowgemm_k<0><<<gT, 512, 0, stream>>>(x, W1p, dinv, hpHi, N);
    gather4_k<<<gG, 256, 0, stream>>>(hpHi, dinv, rowptr, deg, csr, b1, bufB, N);

    // ---- layer 1 ----
    rowgemm_k<1><<<gT, 512, 0, stream>>>(bufB, W2p, dinv, hpHi, N);
    gather4_k<<<gG, 256, 0, stream>>>(hpHi, dinv, rowptr, deg, csr, b2, bufB, N);

    // ---- fused predict MLP (32x32 bf16, 8 waves, 2-matrix LDS staging) ----
    mlp_k<<<gP, 512, 0, stream>>>(bufB, psrc, pdst, P1Ap, P1Bp, pb1, P2p, pb2, P3p, pb3,
                                  pW4, pb4, out, EP);
}

// Round 16
// 161.330 us; speedup vs baseline: 5.8462x; 1.1444x over previous
//
#include <hip/hip_runtime.h>

typedef __attribute__((ext_vector_type(8))) short bf16x8;
typedef __attribute__((ext_vector_type(4))) float f32x4;
typedef __attribute__((ext_vector_type(16))) float f32x16;
typedef __attribute__((ext_vector_type(2))) float f32x2;

// ---- bf16 helpers ----
__device__ __forceinline__ unsigned bfr16(float x) {            // RNE fp32->bf16 bits
    unsigned u = __float_as_uint(x);
    return (u + 0x7fffu + ((u >> 16) & 1u)) >> 16;
}

union U8 { bf16x8 v; unsigned u[4]; };

// fragment from 8 fp32 (round each to bf16)
__device__ __forceinline__ void frag_from_f32(const float* fp, bf16x8& hi) {
    float4 f0 = *(const float4*)fp;
    float4 f1 = *(const float4*)(fp + 4);
    float fv[8] = {f0.x, f0.y, f0.z, f0.w, f1.x, f1.y, f1.z, f1.w};
    U8 H;
    #pragma unroll
    for (int p = 0; p < 4; p++)
        H.u[p] = bfr16(fv[2 * p]) | (bfr16(fv[2 * p + 1]) << 16);
    hi = H.v;
}

// stage one prepped weight matrix (32 KB bf16) into LDS with 512 threads
__device__ __forceinline__ void stage_w512(unsigned short* sm, const unsigned short* Wp, int t) {
    const uint4* src = (const uint4*)Wp;
    uint4* dst = (uint4*)sm;
    #pragma unroll
    for (int p = 0; p < 4; p++) dst[t + p * 512] = src[t + p * 512];
}

__device__ __forceinline__ bf16x8 wfrag_lds(const unsigned short* sm, int f, int lane) {
    return *(const bf16x8*)(sm + f * 512 + lane * 8);
}

// ---- 16x16 path slot map (GCN layers): chan(nt, rho=4g+r) = 32*(nt>>1)+8*g+4*(nt&1)+r
// ---- 32x32 path slot map (MLP): D slot (n, reg, h=lane>>5) <-> true channel
//      c = kt*16 + h*8 + j  with kt = 2n + (reg>>3), j = reg&7
//      => next-layer B-frag(kt) = acc[kt>>1][(kt&1)*8 + j] (register relabel)

// 32x32 layer transition: y(kt) fragment from acc half + bias (+relu), bf16
__device__ __forceinline__ bf16x8 trans32(const f32x16& A, int sb, float4 bva, float4 bvb) {
    float v0 = fmaxf(A[sb + 0] + bva.x, 0.f);
    float v1 = fmaxf(A[sb + 1] + bva.y, 0.f);
    float v2 = fmaxf(A[sb + 2] + bva.z, 0.f);
    float v3 = fmaxf(A[sb + 3] + bva.w, 0.f);
    float v4 = fmaxf(A[sb + 4] + bvb.x, 0.f);
    float v5 = fmaxf(A[sb + 5] + bvb.y, 0.f);
    float v6 = fmaxf(A[sb + 6] + bvb.z, 0.f);
    float v7 = fmaxf(A[sb + 7] + bvb.w, 0.f);
    U8 H;
    H.u[0] = bfr16(v0) | (bfr16(v1) << 16);
    H.u[1] = bfr16(v2) | (bfr16(v3) << 16);
    H.u[2] = bfr16(v4) | (bfr16(v5) << 16);
    H.u[3] = bfr16(v6) | (bfr16(v7) << 16);
    return H.v;
}

// ---------------- CSR build (rank-from-histogram, atomic-free placement) ----------------

__global__ void zero1_k(int* __restrict__ a, int n) {
    int i = blockIdx.x * blockDim.x + threadIdx.x;
    if (i < n) a[i] = 0;
}

__global__ void hist_k(const int* __restrict__ dst, int* __restrict__ deg,
                       int* __restrict__ rank, int E) {
    int e = blockIdx.x * blockDim.x + threadIdx.x;
    if (e < E) rank[e] = atomicAdd(&deg[dst[e]], 1);
}

__global__ void scan1_k(const int* __restrict__ deg, int* __restrict__ rowptr,
                        int* __restrict__ bsum, float* __restrict__ dinv, int n) {
    __shared__ int s[256];
    int tid = threadIdx.x;
    int i = blockIdx.x * 256 + tid;
    int v = (i < n) ? deg[i] : 0;
    s[tid] = v;
    __syncthreads();
    #pragma unroll
    for (int off = 1; off < 256; off <<= 1) {
        int t = (tid >= off) ? s[tid - off] : 0;
        __syncthreads();
        s[tid] += t;
        __syncthreads();
    }
    if (i < n) {
        rowptr[i] = s[tid] - v;
        dinv[i] = rsqrtf((float)(v + 1));
    }
    if (tid == 255) bsum[blockIdx.x] = s[255];
}

__global__ void scan2_k(int* __restrict__ bsum, int nb) {
    __shared__ int s[512];
    int tid = threadIdx.x;
    int v = (tid < nb) ? bsum[tid] : 0;
    s[tid] = v;
    __syncthreads();
    #pragma unroll
    for (int off = 1; off < 512; off <<= 1) {
        int t = (tid >= off) ? s[tid - off] : 0;
        __syncthreads();
        s[tid] += t;
        __syncthreads();
    }
    if (tid < nb) bsum[tid] = s[tid] - v;
}

__global__ void scan3_k(int* __restrict__ rowptr, const int* __restrict__ bsum, int n) {
    int i = blockIdx.x * blockDim.x + threadIdx.x;
    if (i < n) rowptr[i] += bsum[i >> 8];
}

__global__ void place_k(const int* __restrict__ src, const int* __restrict__ dst,
                        const int* __restrict__ rowptr, const int* __restrict__ rank,
                        int* __restrict__ csr, int E) {
    int e = blockIdx.x * blockDim.x + threadIdx.x;
    if (e < E) {
        int pos = rowptr[dst[e]] + rank[e];
        csr[pos] = src[e];
    }
}

// ---- weight prep (bf16 single plane, 16384 u16 per matrix).
// y=0,1 -> 16x16 A-frag format (GCN). y=2..5 -> 32x32 A-frag format (MLP).
__global__ void wprep6_k(const float* __restrict__ s0, const float* __restrict__ s1,
                         const float* __restrict__ s2, const float* __restrict__ s3,
                         const float* __restrict__ s4, const float* __restrict__ s5,
                         unsigned short* __restrict__ dstBase) {
    const float* W;
    switch (blockIdx.y) {
        case 0: W = s0; break; case 1: W = s1; break; case 2: W = s2; break;
        case 3: W = s3; break; case 4: W = s4; break; default: W = s5; break;
    }
    unsigned short* out = dstBase + (size_t)blockIdx.y * 16384;
    int idx = blockIdx.x * 256 + threadIdx.x;
    if (idx >= 16384) return;
    int k = idx >> 7, c = idx & 127;
    unsigned hr = bfr16(W[k * 128 + c]);
    int pos;
    if (blockIdx.y < 2) {
        int kt = k >> 5, gk = (k >> 3) & 3, j = k & 7;
        int nt = ((c >> 5) << 1) | ((c >> 2) & 1);
        int rho = (((c >> 3) & 3) << 2) | (c & 3);
        int lane = (gk << 4) | rho;
        pos = (kt * 8 + nt) * 512 + lane * 8 + j;
    } else {
        int kk = k >> 4, gk = (k >> 3) & 1, jj = k & 7;
        int ktc = c >> 4, hc = (c >> 3) & 1, jc = c & 7;
        int n = ktc >> 1;
        int reg = ((ktc & 1) << 3) | jc;
        int m = (reg & 3) + 8 * (reg >> 2) + 4 * hc;
        int lane = (gk << 5) | m;
        pos = (kk * 4 + n) * 512 + lane * 8 + jj;
    }
    out[pos] = (unsigned short)hr;
}

// ---- gather aggregate: out[i] = relu(bias + dinv[i]*(hp[i] + sum_in hp[s])).
// hp = FP8 e4m3 plane (1 B/chan, HW cvt). 4 nodes/wave, 16 lanes x 8 chans; 8-deep unroll.
// Output bf16 plane.
__global__ __launch_bounds__(256)
void gather4_k(const unsigned char* __restrict__ hp, const float* __restrict__ dinv,
               const int* __restrict__ rowptr, const int* __restrict__ deg,
               const int* __restrict__ csr, const float* __restrict__ bias,
               unsigned short* __restrict__ out, int N)
{
    int tid = threadIdx.x;
    int lane = tid & 63;
    int grp = lane >> 4, cl = lane & 15;
    int i = blockIdx.x * 16 + (tid >> 6) * 4 + grp;
    if (i >= N) return;
    int c8 = cl * 8;
    uint2 p = *(const uint2*)(hp + (size_t)i * 128 + c8);
    f32x2 d0 = __builtin_amdgcn_cvt_pk_f32_fp8(p.x, false);
    f32x2 d1 = __builtin_amdgcn_cvt_pk_f32_fp8(p.x, true);
    f32x2 d2 = __builtin_amdgcn_cvt_pk_f32_fp8(p.y, false);
    f32x2 d3 = __builtin_amdgcn_cvt_pk_f32_fp8(p.y, true);
    float a0 = d0.x, a1 = d0.y, a2 = d1.x, a3 = d1.y;
    float a4 = d2.x, a5 = d2.y, a6 = d3.x, a7 = d3.y;
    int beg = rowptr[i], dg = deg[i];
    int j = 0;
    for (; j + 7 < dg; j += 8) {
        uint2 q[8];
        #pragma unroll
        for (int u = 0; u < 8; u++) {
            int su = csr[beg + j + u];
            q[u] = *(const uint2*)(hp + (size_t)su * 128 + c8);
        }
        #pragma unroll
        for (int u = 0; u < 8; u++) {
            f32x2 e0 = __builtin_amdgcn_cvt_pk_f32_fp8(q[u].x, false);
            f32x2 e1 = __builtin_amdgcn_cvt_pk_f32_fp8(q[u].x, true);
            f32x2 e2 = __builtin_amdgcn_cvt_pk_f32_fp8(q[u].y, false);
            f32x2 e3 = __builtin_amdgcn_cvt_pk_f32_fp8(q[u].y, true);
            a0 += e0.x; a1 += e0.y; a2 += e1.x; a3 += e1.y;
            a4 += e2.x; a5 += e2.y; a6 += e3.x; a7 += e3.y;
        }
    }
    for (; j + 3 < dg; j += 4) {
        uint2 q[4];
        #pragma unroll
        for (int u = 0; u < 4; u++) {
            int su = csr[beg + j + u];
            q[u] = *(const uint2*)(hp + (size_t)su * 128 + c8);
        }
        #pragma unroll
        for (int u = 0; u < 4; u++) {
            f32x2 e0 = __builtin_amdgcn_cvt_pk_f32_fp8(q[u].x, false);
            f32x2 e1 = __builtin_amdgcn_cvt_pk_f32_fp8(q[u].x, true);
            f32x2 e2 = __builtin_amdgcn_cvt_pk_f32_fp8(q[u].y, false);
            f32x2 e3 = __builtin_amdgcn_cvt_pk_f32_fp8(q[u].y, true);
            a0 += e0.x; a1 += e0.y; a2 += e1.x; a3 += e1.y;
            a4 += e2.x; a5 += e2.y; a6 += e3.x; a7 += e3.y;
        }
    }
    for (; j < dg; j++) {
        int s0 = csr[beg + j];
        uint2 q0 = *(const uint2*)(hp + (size_t)s0 * 128 + c8);
        f32x2 e0 = __builtin_amdgcn_cvt_pk_f32_fp8(q0.x, false);
        f32x2 e1 = __builtin_amdgcn_cvt_pk_f32_fp8(q0.x, true);
        f32x2 e2 = __builtin_amdgcn_cvt_pk_f32_fp8(q0.y, false);
        f32x2 e3 = __builtin_amdgcn_cvt_pk_f32_fp8(q0.y, true);
        a0 += e0.x; a1 += e0.y; a2 += e1.x; a3 += e1.y;
        a4 += e2.x; a5 += e2.y; a6 += e3.x; a7 += e3.y;
    }
    float di = dinv[i];
    float4 bv0 = *(const float4*)(bias + c8);
    float4 bv1 = *(const float4*)(bias + c8 + 4);
    uint4 o;
    o.x = bfr16(fmaxf(bv0.x + di * a0, 0.f)) | (bfr16(fmaxf(bv0.y + di * a1, 0.f)) << 16);
    o.y = bfr16(fmaxf(bv0.z + di * a2, 0.f)) | (bfr16(fmaxf(bv0.w + di * a3, 0.f)) << 16);
    o.z = bfr16(fmaxf(bv1.x + di * a4, 0.f)) | (bfr16(fmaxf(bv1.y + di * a5, 0.f)) << 16);
    o.w = bfr16(fmaxf(bv1.z + di * a6, 0.f)) | (bfr16(fmaxf(bv1.w + di * a7, 0.f)) << 16);
    *(uint4*)(out + (size_t)i * 128 + c8) = o;
}

// ---- layer GEMM (16x16 path): Chp = dinv ⊙ (A @ W) as FP8 e4m3 plane. 1 MFMA/frag. ----
template<int AMODE>   // 0: A fp32 ; 1: A bf16 plane
__global__ __launch_bounds__(512)
void rowgemm_k(const void* __restrict__ Asrc, const unsigned short* __restrict__ Wp,
               const float* __restrict__ rowScale, unsigned char* __restrict__ CoutF8, int M)
{
    __shared__ __align__(16) unsigned short smw[16384];   // 32 KB: one bf16 weight matrix
    const int t = threadIdx.x, lane = t & 63, wave = t >> 6;
    const int base = blockIdx.x * 128 + wave * 16;
    const int s = lane & 15, g = lane >> 4, kg = g * 8;
    const int arow = base + s;
    const int rowc = (arow < M) ? arow : (M - 1);

    stage_w512(smw, Wp, t);

    bf16x8 yh[4];
    #pragma unroll
    for (int kt = 0; kt < 4; kt++) {
        if (AMODE == 1)
            yh[kt] = *(const bf16x8*)((const unsigned short*)Asrc + (size_t)rowc * 128 + kt * 32 + kg);
        else
            frag_from_f32((const float*)Asrc + (size_t)rowc * 128 + kt * 32 + kg, yh[kt]);
    }
    __syncthreads();

    f32x4 acc[8];
    #pragma unroll
    for (int nt = 0; nt < 8; nt++) acc[nt] = (f32x4){0.f, 0.f, 0.f, 0.f};

    #pragma unroll
    for (int kt = 0; kt < 4; kt++) {
        #pragma unroll
        for (int nt = 0; nt < 8; nt++) {
            bf16x8 whi = wfrag_lds(smw, kt * 8 + nt, lane);
            acc[nt] = __builtin_amdgcn_mfma_f32_16x16x32_bf16(whi, yh[kt], acc[nt], 0, 0, 0);
        }
    }

    if (arow < M) {
        float sc = rowScale[arow];
        #pragma unroll
        for (int nt = 0; nt < 8; nt++) {
            int cbase = 32 * (nt >> 1) + 8 * g + 4 * (nt & 1);
            int r = 0;
            r = __builtin_amdgcn_cvt_pk_fp8_f32(acc[nt][0] * sc, acc[nt][1] * sc, r, false);
            r = __builtin_amdgcn_cvt_pk_fp8_f32(acc[nt][2] * sc, acc[nt][3] * sc, r, true);
            *(unsigned*)(CoutF8 + (size_t)arow * 128 + cbase) = (unsigned)r;
        }
    }
}

// ---- fused predict MLP (32x32x16, bf16): gather xi/xj -> y1 -> y2 -> y3 -> dot -> out.
// 32 samples/wave, 8 waves (256 samples/block). TWO weight matrices in LDS at a time:
// stage {W1a,W1b} -> layer 1 ; stage {W2,W3} -> layers 2+3 (no intervening barrier).
__global__ __launch_bounds__(512)
void mlp_k(const unsigned short* __restrict__ X, const int* __restrict__ psrc, const int* __restrict__ pdst,
           const unsigned short* __restrict__ W1a, const unsigned short* __restrict__ W1b,
           const float* __restrict__ b1, const unsigned short* __restrict__ W2p,
           const float* __restrict__ b2, const unsigned short* __restrict__ W3p,
           const float* __restrict__ b3, const float* __restrict__ w4,
           const float* __restrict__ b4p, float* __restrict__ out, int M)
{
    __shared__ __align__(16) unsigned short smw[2][16384];   // 64 KB: two weight matrices
    const int t = threadIdx.x, lane = t & 63, wave = t >> 6;
    const int base = blockIdx.x * 256 + wave * 32;
    const int s = lane & 31, h8 = (lane >> 5) * 8;
    const int arow = base + s;
    const int rowc = (arow < M) ? arow : (M - 1);
    const int si = psrc[rowc], sj = pdst[rowc];

    // issue all X loads upfront (hide HBM latency under the 64 KB staging)
    bf16x8 xi[8], xj[8];
    #pragma unroll
    for (int kt = 0; kt < 8; kt++)
        xi[kt] = *(const bf16x8*)(X + (size_t)si * 128 + kt * 16 + h8);
    #pragma unroll
    for (int kt = 0; kt < 8; kt++)
        xj[kt] = *(const bf16x8*)(X + (size_t)sj * 128 + kt * 16 + h8);

    stage_w512(smw[0], W1a, t);
    stage_w512(smw[1], W1b, t);
    __syncthreads();

    // ---- layer 1: acc1 = W1a^T xi + W1b^T xj ----
    f32x16 acc1[4];
    #pragma unroll
    for (int nt = 0; nt < 4; nt++)
        #pragma unroll
        for (int q = 0; q < 16; q++) acc1[nt][q] = 0.f;
    #pragma unroll
    for (int kt = 0; kt < 8; kt++) {
        #pragma unroll
        for (int nt = 0; nt < 4; nt++) {
            bf16x8 wa = wfrag_lds(smw[0], kt * 4 + nt, lane);
            acc1[nt] = __builtin_amdgcn_mfma_f32_32x32x16_bf16(wa, xi[kt], acc1[nt], 0, 0, 0);
            bf16x8 wb = wfrag_lds(smw[1], kt * 4 + nt, lane);
            acc1[nt] = __builtin_amdgcn_mfma_f32_32x32x16_bf16(wb, xj[kt], acc1[nt], 0, 0, 0);
        }
    }
    __syncthreads();

    stage_w512(smw[0], W2p, t);
    stage_w512(smw[1], W3p, t);
    __syncthreads();

    // ---- layer 2 ----
    f32x16 acc2[4];
    #pragma unroll
    for (int nt = 0; nt < 4; nt++)
        #pragma unroll
        for (int q = 0; q < 16; q++) acc2[nt][q] = 0.f;
    #pragma unroll
    for (int kt = 0; kt < 8; kt++) {
        float4 bva = *(const float4*)(b1 + kt * 16 + h8);
        float4 bvb = *(const float4*)(b1 + kt * 16 + h8 + 4);
        bf16x8 yh = trans32(acc1[kt >> 1], (kt & 1) * 8, bva, bvb);
        #pragma unroll
        for (int nt = 0; nt < 4; nt++) {
            bf16x8 whi = wfrag_lds(smw[0], kt * 4 + nt, lane);
            acc2[nt] = __builtin_amdgcn_mfma_f32_32x32x16_bf16(whi, yh, acc2[nt], 0, 0, 0);
        }
    }

    // ---- layer 3 (W3 already staged; no barrier) ----
    f32x16 acc3[4];
    #pragma unroll
    for (int nt = 0; nt < 4; nt++)
        #pragma unroll
        for (int q = 0; q < 16; q++) acc3[nt][q] = 0.f;
    #pragma unroll
    for (int kt = 0; kt < 8; kt++) {
        float4 bva = *(const float4*)(b2 + kt * 16 + h8);
        float4 bvb = *(const float4*)(b2 + kt * 16 + h8 + 4);
        bf16x8 yh = trans32(acc2[kt >> 1], (kt & 1) * 8, bva, bvb);
        #pragma unroll
        for (int nt = 0; nt < 4; nt++) {
            bf16x8 whi = wfrag_lds(smw[1], kt * 4 + nt, lane);
            acc3[nt] = __builtin_amdgcn_mfma_f32_32x32x16_bf16(whi, yh, acc3[nt], 0, 0, 0);
        }
    }

    // ---- final: out = relu( sum_c relu(y3[c]) * w4[c] + b4 ) ----
    float p = 0.f;
    #pragma unroll
    for (int nt = 0; nt < 4; nt++) {
        int c1 = 32 * nt + h8;
        int c2 = 32 * nt + 16 + h8;
        float4 b3a = *(const float4*)(b3 + c1);
        float4 b3b = *(const float4*)(b3 + c1 + 4);
        float4 b3c = *(const float4*)(b3 + c2);
        float4 b3d = *(const float4*)(b3 + c2 + 4);
        float4 w4a = *(const float4*)(w4 + c1);
        float4 w4b = *(const float4*)(w4 + c1 + 4);
        float4 w4c = *(const float4*)(w4 + c2);
        float4 w4d = *(const float4*)(w4 + c2 + 4);
        p += fmaxf(acc3[nt][0]  + b3a.x, 0.f) * w4a.x;
        p += fmaxf(acc3[nt][1]  + b3a.y, 0.f) * w4a.y;
        p += fmaxf(acc3[nt][2]  + b3a.z, 0.f) * w4a.z;
        p += fmaxf(acc3[nt][3]  + b3a.w, 0.f) * w4a.w;
        p += fmaxf(acc3[nt][4]  + b3b.x, 0.f) * w4b.x;
        p += fmaxf(acc3[nt][5]  + b3b.y, 0.f) * w4b.y;
        p += fmaxf(acc3[nt][6]  + b3b.z, 0.f) * w4b.z;
        p += fmaxf(acc3[nt][7]  + b3b.w, 0.f) * w4b.w;
        p += fmaxf(acc3[nt][8]  + b3c.x, 0.f) * w4c.x;
        p += fmaxf(acc3[nt][9]  + b3c.y, 0.f) * w4c.y;
        p += fmaxf(acc3[nt][10] + b3c.z, 0.f) * w4c.z;
        p += fmaxf(acc3[nt][11] + b3c.w, 0.f) * w4c.w;
        p += fmaxf(acc3[nt][12] + b3d.x, 0.f) * w4d.x;
        p += fmaxf(acc3[nt][13] + b3d.y, 0.f) * w4d.y;
        p += fmaxf(acc3[nt][14] + b3d.z, 0.f) * w4d.z;
        p += fmaxf(acc3[nt][15] + b3d.w, 0.f) * w4d.w;
    }
    p += __shfl_xor(p, 32, 64);
    if (lane < 32 && arow < M) out[arow] = fmaxf(p + b4p[0], 0.f);
}

extern "C" void kernel_launch(void* const* d_in, const int* in_sizes, int n_in,
                              void* d_out, int out_size, void* d_ws, size_t ws_size,
                              hipStream_t stream)
{
    const float* x   = (const float*)d_in[0];
    const int*   ei  = (const int*)d_in[2];
    const int*   pei = (const int*)d_in[3];
    const float* W1  = (const float*)d_in[4];
    const float* b1  = (const float*)d_in[5];
    const float* W2  = (const float*)d_in[6];
    const float* b2  = (const float*)d_in[7];
    // d_in[8..11] = edge_mlp weights: dead w.r.t. output, skipped
    const float* pW1 = (const float*)d_in[12];
    const float* pb1 = (const float*)d_in[13];
    const float* pW2 = (const float*)d_in[14];
    const float* pb2 = (const float*)d_in[15];
    const float* pW3 = (const float*)d_in[16];
    const float* pb3 = (const float*)d_in[17];
    const float* pW4 = (const float*)d_in[18];
    const float* pb4 = (const float*)d_in[19];

    const int N  = in_sizes[0] / 128;
    const int E  = in_sizes[2] / 2;
    const int EP = in_sizes[3] / 2;
    const int Npad = (N + 255) & ~255;

    float*          ws     = (float*)d_ws;
    float*          dinv   = ws;                                    // Npad floats
    unsigned char*  hpF8   = (unsigned char*)(ws + Npad);           // N*128 bytes (fp8 plane)
    unsigned short* bufB   = (unsigned short*)(hpF8 + (size_t)N * 128);  // N*128 u16 (bf16 plane)
    size_t ioff = (((size_t)(bufB + (size_t)N * 128)) + 255) & ~(size_t)255;
    int*   deg    = (int*)ioff;                                     // Npad
    int*   rowptr = deg + Npad;                                     // Npad
    int*   rank   = rowptr + Npad;                                  // E
    int*   csr    = rank + E;                                       // E
    int*   bsum   = csr + E;                                        // 512
    size_t wpOff = ((size_t)(bsum + 512) + 15) & ~(size_t)15;
    unsigned short* wp = (unsigned short*)wpOff;                    // 6 x 16384 u16
    unsigned short* W1p  = wp;
    unsigned short* W2p  = wp + 16384;
    unsigned short* P1Ap = wp + 2 * 16384;
    unsigned short* P1Bp = wp + 3 * 16384;
    unsigned short* P2p  = wp + 4 * 16384;
    unsigned short* P3p  = wp + 5 * 16384;
    float* out = (float*)d_out;

    const int* esrc = ei;
    const int* edst = ei + E;
    const int* psrc = pei;
    const int* pdst = pei + EP;

    const int nb = (N + 255) / 256;
    const int gN = (N + 255) / 256;
    const int gE = (E + 255) / 256;
    const int gT = (N + 127) / 128;
    const int gP = (EP + 255) / 256;    // 256 samples per block (8 waves x 32)
    const int gG = (N + 15) / 16;

    // ---- CSR build + dinv (atomic-free placement via rank) ----
    zero1_k<<<gN, 256, 0, stream>>>(deg, N);
    hist_k<<<gE, 256, 0, stream>>>(edst, deg, rank, E);
    scan1_k<<<nb, 256, 0, stream>>>(deg, rowptr, bsum, dinv, N);
    scan2_k<<<1, 512, 0, stream>>>(bsum, nb);
    scan3_k<<<gN, 256, 0, stream>>>(rowptr, bsum, N);
    place_k<<<gE, 256, 0, stream>>>(esrc, edst, rowptr, rank, csr, E);

    // ---- weight prep (bf16, dual fragment format) ----
    wprep6_k<<<dim3(64, 6), 256, 0, stream>>>(W1, W2, pW1, pW1 + 128 * 128, pW2, pW3, wp);

    // ---- layer 0: hp1 = dinv ⊙ (x@W1) [fp8]; x1r = relu(agg + b1) [bf16] ----
    rowgemm_k<0><<<gT, 512, 0, stream>>>(x, W1p, dinv, hpF8, N);
    gather4_k<<<gG, 256, 0, stream>>>(hpF8, dinv, rowptr, deg, csr, b1, bufB, N);

    // ---- layer 1 ----
    rowgemm_k<1><<<gT, 512, 0, stream>>>(bufB, W2p, dinv, hpF8, N);
    gather4_k<<<gG, 256, 0, stream>>>(hpF8, dinv, rowptr, deg, csr, b2, bufB, N);

    // ---- fused predict MLP (32x32 bf16, 8 waves, 2-matrix LDS staging) ----
    mlp_k<<<gP, 512, 0, stream>>>(bufB, psrc, pdst, P1Ap, P1Bp, pb1, P2p, pb2, P3p, pb3,
                                  pW4, pb4, out, EP);
}

// Round 17
// 153.547 us; speedup vs baseline: 6.1425x; 1.0507x over previous
//
#include <hip/hip_runtime.h>

typedef __attribute__((ext_vector_type(8))) short bf16x8;
typedef __attribute__((ext_vector_type(4))) float f32x4;
typedef __attribute__((ext_vector_type(16))) float f32x16;
typedef __attribute__((ext_vector_type(2))) float f32x2;

// ---- bf16 helpers ----
__device__ __forceinline__ unsigned bfr16(float x) {            // RNE fp32->bf16 bits
    unsigned u = __float_as_uint(x);
    return (u + 0x7fffu + ((u >> 16) & 1u)) >> 16;
}

union U8 { bf16x8 v; unsigned u[4]; };

// fragment from 8 fp32 (round each to bf16)
__device__ __forceinline__ void frag_from_f32(const float* fp, bf16x8& hi) {
    float4 f0 = *(const float4*)fp;
    float4 f1 = *(const float4*)(fp + 4);
    float fv[8] = {f0.x, f0.y, f0.z, f0.w, f1.x, f1.y, f1.z, f1.w};
    U8 H;
    #pragma unroll
    for (int p = 0; p < 4; p++)
        H.u[p] = bfr16(fv[2 * p]) | (bfr16(fv[2 * p + 1]) << 16);
    hi = H.v;
}

// fragment from 8 fp8 e4m3 (HW cvt; e4m3 is exactly representable in bf16)
__device__ __forceinline__ bf16x8 frag_from_f8(const unsigned char* p) {
    uint2 q = *(const uint2*)p;
    f32x2 e0 = __builtin_amdgcn_cvt_pk_f32_fp8(q.x, false);
    f32x2 e1 = __builtin_amdgcn_cvt_pk_f32_fp8(q.x, true);
    f32x2 e2 = __builtin_amdgcn_cvt_pk_f32_fp8(q.y, false);
    f32x2 e3 = __builtin_amdgcn_cvt_pk_f32_fp8(q.y, true);
    U8 H;
    H.u[0] = bfr16(e0.x) | (bfr16(e0.y) << 16);
    H.u[1] = bfr16(e1.x) | (bfr16(e1.y) << 16);
    H.u[2] = bfr16(e2.x) | (bfr16(e2.y) << 16);
    H.u[3] = bfr16(e3.x) | (bfr16(e3.y) << 16);
    return H.v;
}

// stage one prepped weight matrix (32 KB bf16) into LDS with 512 threads
__device__ __forceinline__ void stage_w512(unsigned short* sm, const unsigned short* Wp, int t) {
    const uint4* src = (const uint4*)Wp;
    uint4* dst = (uint4*)sm;
    #pragma unroll
    for (int p = 0; p < 4; p++) dst[t + p * 512] = src[t + p * 512];
}

__device__ __forceinline__ bf16x8 wfrag_lds(const unsigned short* sm, int f, int lane) {
    return *(const bf16x8*)(sm + f * 512 + lane * 8);
}

// ---- 16x16 path slot map (GCN layers): chan(nt, rho=4g+r) = 32*(nt>>1)+8*g+4*(nt&1)+r
// ---- 32x32 path slot map (MLP): D slot (n, reg, h=lane>>5) <-> true channel
//      c = kt*16 + h*8 + j  with kt = 2n + (reg>>3), j = reg&7
//      => next-layer B-frag(kt) = acc[kt>>1][(kt&1)*8 + j] (register relabel)

// 32x32 layer transition: y(kt) fragment from acc half + bias (+relu), bf16
__device__ __forceinline__ bf16x8 trans32(const f32x16& A, int sb, float4 bva, float4 bvb) {
    float v0 = fmaxf(A[sb + 0] + bva.x, 0.f);
    float v1 = fmaxf(A[sb + 1] + bva.y, 0.f);
    float v2 = fmaxf(A[sb + 2] + bva.z, 0.f);
    float v3 = fmaxf(A[sb + 3] + bva.w, 0.f);
    float v4 = fmaxf(A[sb + 4] + bvb.x, 0.f);
    float v5 = fmaxf(A[sb + 5] + bvb.y, 0.f);
    float v6 = fmaxf(A[sb + 6] + bvb.z, 0.f);
    float v7 = fmaxf(A[sb + 7] + bvb.w, 0.f);
    U8 H;
    H.u[0] = bfr16(v0) | (bfr16(v1) << 16);
    H.u[1] = bfr16(v2) | (bfr16(v3) << 16);
    H.u[2] = bfr16(v4) | (bfr16(v5) << 16);
    H.u[3] = bfr16(v6) | (bfr16(v7) << 16);
    return H.v;
}

// ---------------- CSR build (rank-from-histogram, atomic-free placement) ----------------

__global__ void zero1_k(int* __restrict__ a, int n) {
    int i = blockIdx.x * blockDim.x + threadIdx.x;
    if (i < n) a[i] = 0;
}

__global__ void hist_k(const int* __restrict__ dst, int* __restrict__ deg,
                       int* __restrict__ rank, int E) {
    int e = blockIdx.x * blockDim.x + threadIdx.x;
    if (e < E) rank[e] = atomicAdd(&deg[dst[e]], 1);
}

__global__ void scan1_k(const int* __restrict__ deg, int* __restrict__ rowptr,
                        int* __restrict__ bsum, float* __restrict__ dinv, int n) {
    __shared__ int s[256];
    int tid = threadIdx.x;
    int i = blockIdx.x * 256 + tid;
    int v = (i < n) ? deg[i] : 0;
    s[tid] = v;
    __syncthreads();
    #pragma unroll
    for (int off = 1; off < 256; off <<= 1) {
        int t = (tid >= off) ? s[tid - off] : 0;
        __syncthreads();
        s[tid] += t;
        __syncthreads();
    }
    if (i < n) {
        rowptr[i] = s[tid] - v;
        dinv[i] = rsqrtf((float)(v + 1));
    }
    if (tid == 255) bsum[blockIdx.x] = s[255];
}

__global__ void scan2_k(int* __restrict__ bsum, int nb) {
    __shared__ int s[512];
    int tid = threadIdx.x;
    int v = (tid < nb) ? bsum[tid] : 0;
    s[tid] = v;
    __syncthreads();
    #pragma unroll
    for (int off = 1; off < 512; off <<= 1) {
        int t = (tid >= off) ? s[tid - off] : 0;
        __syncthreads();
        s[tid] += t;
        __syncthreads();
    }
    if (tid < nb) bsum[tid] = s[tid] - v;
}

__global__ void scan3_k(int* __restrict__ rowptr, const int* __restrict__ bsum, int n) {
    int i = blockIdx.x * blockDim.x + threadIdx.x;
    if (i < n) rowptr[i] += bsum[i >> 8];
}

__global__ void place_k(const int* __restrict__ src, const int* __restrict__ dst,
                        const int* __restrict__ rowptr, const int* __restrict__ rank,
                        int* __restrict__ csr, int E) {
    int e = blockIdx.x * blockDim.x + threadIdx.x;
    if (e < E) {
        int pos = rowptr[dst[e]] + rank[e];
        csr[pos] = src[e];
    }
}

// ---- weight prep (bf16 single plane, 16384 u16 per matrix).
// y=0,1 -> 16x16 A-frag format (GCN). y=2..5 -> 32x32 A-frag format (MLP).
__global__ void wprep6_k(const float* __restrict__ s0, const float* __restrict__ s1,
                         const float* __restrict__ s2, const float* __restrict__ s3,
                         const float* __restrict__ s4, const float* __restrict__ s5,
                         unsigned short* __restrict__ dstBase) {
    const float* W;
    switch (blockIdx.y) {
        case 0: W = s0; break; case 1: W = s1; break; case 2: W = s2; break;
        case 3: W = s3; break; case 4: W = s4; break; default: W = s5; break;
    }
    unsigned short* out = dstBase + (size_t)blockIdx.y * 16384;
    int idx = blockIdx.x * 256 + threadIdx.x;
    if (idx >= 16384) return;
    int k = idx >> 7, c = idx & 127;
    unsigned hr = bfr16(W[k * 128 + c]);
    int pos;
    if (blockIdx.y < 2) {
        int kt = k >> 5, gk = (k >> 3) & 3, j = k & 7;
        int nt = ((c >> 5) << 1) | ((c >> 2) & 1);
        int rho = (((c >> 3) & 3) << 2) | (c & 3);
        int lane = (gk << 4) | rho;
        pos = (kt * 8 + nt) * 512 + lane * 8 + j;
    } else {
        int kk = k >> 4, gk = (k >> 3) & 1, jj = k & 7;
        int ktc = c >> 4, hc = (c >> 3) & 1, jc = c & 7;
        int n = ktc >> 1;
        int reg = ((ktc & 1) << 3) | jc;
        int m = (reg & 3) + 8 * (reg >> 2) + 4 * hc;
        int lane = (gk << 5) | m;
        pos = (kk * 4 + n) * 512 + lane * 8 + jj;
    }
    out[pos] = (unsigned short)hr;
}

// ---- gather aggregate: out[i] = relu(bias + dinv[i]*(hp[i] + sum_in hp[s])).
// hp = FP8 e4m3 plane. OUTFMT 0: bf16 plane out (16B/lane). OUTFMT 1: fp8 plane out (8B/lane).
template<int OUTFMT>
__global__ __launch_bounds__(256)
void gather4_k(const unsigned char* __restrict__ hp, const float* __restrict__ dinv,
               const int* __restrict__ rowptr, const int* __restrict__ deg,
               const int* __restrict__ csr, const float* __restrict__ bias,
               void* __restrict__ outPtr, int N)
{
    int tid = threadIdx.x;
    int lane = tid & 63;
    int grp = lane >> 4, cl = lane & 15;
    int i = blockIdx.x * 16 + (tid >> 6) * 4 + grp;
    if (i >= N) return;
    int c8 = cl * 8;
    uint2 p = *(const uint2*)(hp + (size_t)i * 128 + c8);
    f32x2 d0 = __builtin_amdgcn_cvt_pk_f32_fp8(p.x, false);
    f32x2 d1 = __builtin_amdgcn_cvt_pk_f32_fp8(p.x, true);
    f32x2 d2 = __builtin_amdgcn_cvt_pk_f32_fp8(p.y, false);
    f32x2 d3 = __builtin_amdgcn_cvt_pk_f32_fp8(p.y, true);
    float a0 = d0.x, a1 = d0.y, a2 = d1.x, a3 = d1.y;
    float a4 = d2.x, a5 = d2.y, a6 = d3.x, a7 = d3.y;
    int beg = rowptr[i], dg = deg[i];
    int j = 0;
    for (; j + 7 < dg; j += 8) {
        uint2 q[8];
        #pragma unroll
        for (int u = 0; u < 8; u++) {
            int su = csr[beg + j + u];
            q[u] = *(const uint2*)(hp + (size_t)su * 128 + c8);
        }
        #pragma unroll
        for (int u = 0; u < 8; u++) {
            f32x2 e0 = __builtin_amdgcn_cvt_pk_f32_fp8(q[u].x, false);
            f32x2 e1 = __builtin_amdgcn_cvt_pk_f32_fp8(q[u].x, true);
            f32x2 e2 = __builtin_amdgcn_cvt_pk_f32_fp8(q[u].y, false);
            f32x2 e3 = __builtin_amdgcn_cvt_pk_f32_fp8(q[u].y, true);
            a0 += e0.x; a1 += e0.y; a2 += e1.x; a3 += e1.y;
            a4 += e2.x; a5 += e2.y; a6 += e3.x; a7 += e3.y;
        }
    }
    for (; j + 3 < dg; j += 4) {
        uint2 q[4];
        #pragma unroll
        for (int u = 0; u < 4; u++) {
            int su = csr[beg + j + u];
            q[u] = *(const uint2*)(hp + (size_t)su * 128 + c8);
        }
        #pragma unroll
        for (int u = 0; u < 4; u++) {
            f32x2 e0 = __builtin_amdgcn_cvt_pk_f32_fp8(q[u].x, false);
            f32x2 e1 = __builtin_amdgcn_cvt_pk_f32_fp8(q[u].x, true);
            f32x2 e2 = __builtin_amdgcn_cvt_pk_f32_fp8(q[u].y, false);
            f32x2 e3 = __builtin_amdgcn_cvt_pk_f32_fp8(q[u].y, true);
            a0 += e0.x; a1 += e0.y; a2 += e1.x; a3 += e1.y;
            a4 += e2.x; a5 += e2.y; a6 += e3.x; a7 += e3.y;
        }
    }
    for (; j < dg; j++) {
        int s0 = csr[beg + j];
        uint2 q0 = *(const uint2*)(hp + (size_t)s0 * 128 + c8);
        f32x2 e0 = __builtin_amdgcn_cvt_pk_f32_fp8(q0.x, false);
        f32x2 e1 = __builtin_amdgcn_cvt_pk_f32_fp8(q0.x, true);
        f32x2 e2 = __builtin_amdgcn_cvt_pk_f32_fp8(q0.y, false);
        f32x2 e3 = __builtin_amdgcn_cvt_pk_f32_fp8(q0.y, true);
        a0 += e0.x; a1 += e0.y; a2 += e1.x; a3 += e1.y;
        a4 += e2.x; a5 += e2.y; a6 += e3.x; a7 += e3.y;
    }
    float di = dinv[i];
    float4 bv0 = *(const float4*)(bias + c8);
    float4 bv1 = *(const float4*)(bias + c8 + 4);
    float v0 = fmaxf(bv0.x + di * a0, 0.f);
    float v1 = fmaxf(bv0.y + di * a1, 0.f);
    float v2 = fmaxf(bv0.z + di * a2, 0.f);
    float v3 = fmaxf(bv0.w + di * a3, 0.f);
    float v4 = fmaxf(bv1.x + di * a4, 0.f);
    float v5 = fmaxf(bv1.y + di * a5, 0.f);
    float v6 = fmaxf(bv1.z + di * a6, 0.f);
    float v7 = fmaxf(bv1.w + di * a7, 0.f);
    if (OUTFMT == 0) {
        uint4 o;
        o.x = bfr16(v0) | (bfr16(v1) << 16);
        o.y = bfr16(v2) | (bfr16(v3) << 16);
        o.z = bfr16(v4) | (bfr16(v5) << 16);
        o.w = bfr16(v6) | (bfr16(v7) << 16);
        *(uint4*)((unsigned short*)outPtr + (size_t)i * 128 + c8) = o;
    } else {
        int r0 = 0, r1 = 0;
        r0 = __builtin_amdgcn_cvt_pk_fp8_f32(v0, v1, r0, false);
        r0 = __builtin_amdgcn_cvt_pk_fp8_f32(v2, v3, r0, true);
        r1 = __builtin_amdgcn_cvt_pk_fp8_f32(v4, v5, r1, false);
        r1 = __builtin_amdgcn_cvt_pk_fp8_f32(v6, v7, r1, true);
        uint2 o = make_uint2((unsigned)r0, (unsigned)r1);
        *(uint2*)((unsigned char*)outPtr + (size_t)i * 128 + c8) = o;
    }
}

// ---- layer GEMM (16x16 path): Chp = dinv ⊙ (A @ W) as FP8 e4m3 plane. 1 MFMA/frag. ----
template<int AMODE>   // 0: A fp32 ; 1: A bf16 plane
__global__ __launch_bounds__(512)
void rowgemm_k(const void* __restrict__ Asrc, const unsigned short* __restrict__ Wp,
               const float* __restrict__ rowScale, unsigned char* __restrict__ CoutF8, int M)
{
    __shared__ __align__(16) unsigned short smw[16384];   // 32 KB: one bf16 weight matrix
    const int t = threadIdx.x, lane = t & 63, wave = t >> 6;
    const int base = blockIdx.x * 128 + wave * 16;
    const int s = lane & 15, g = lane >> 4, kg = g * 8;
    const int arow = base + s;
    const int rowc = (arow < M) ? arow : (M - 1);

    stage_w512(smw, Wp, t);

    bf16x8 yh[4];
    #pragma unroll
    for (int kt = 0; kt < 4; kt++) {
        if (AMODE == 1)
            yh[kt] = *(const bf16x8*)((const unsigned short*)Asrc + (size_t)rowc * 128 + kt * 32 + kg);
        else
            frag_from_f32((const float*)Asrc + (size_t)rowc * 128 + kt * 32 + kg, yh[kt]);
    }
    __syncthreads();

    f32x4 acc[8];
    #pragma unroll
    for (int nt = 0; nt < 8; nt++) acc[nt] = (f32x4){0.f, 0.f, 0.f, 0.f};

    #pragma unroll
    for (int kt = 0; kt < 4; kt++) {
        #pragma unroll
        for (int nt = 0; nt < 8; nt++) {
            bf16x8 whi = wfrag_lds(smw, kt * 8 + nt, lane);
            acc[nt] = __builtin_amdgcn_mfma_f32_16x16x32_bf16(whi, yh[kt], acc[nt], 0, 0, 0);
        }
    }

    if (arow < M) {
        float sc = rowScale[arow];
        #pragma unroll
        for (int nt = 0; nt < 8; nt++) {
            int cbase = 32 * (nt >> 1) + 8 * g + 4 * (nt & 1);
            int r = 0;
            r = __builtin_amdgcn_cvt_pk_fp8_f32(acc[nt][0] * sc, acc[nt][1] * sc, r, false);
            r = __builtin_amdgcn_cvt_pk_fp8_f32(acc[nt][2] * sc, acc[nt][3] * sc, r, true);
            *(unsigned*)(CoutF8 + (size_t)arow * 128 + cbase) = (unsigned)r;
        }
    }
}

// ---- fused predict MLP (32x32x16, bf16 compute): gather xi/xj (fp8) -> y1 -> y2 -> y3 -> dot.
// 32 samples/wave, 8 waves (256 samples/block). TWO weight matrices in LDS at a time.
__global__ __launch_bounds__(512)
void mlp_k(const unsigned char* __restrict__ X, const int* __restrict__ psrc, const int* __restrict__ pdst,
           const unsigned short* __restrict__ W1a, const unsigned short* __restrict__ W1b,
           const float* __restrict__ b1, const unsigned short* __restrict__ W2p,
           const float* __restrict__ b2, const unsigned short* __restrict__ W3p,
           const float* __restrict__ b3, const float* __restrict__ w4,
           const float* __restrict__ b4p, float* __restrict__ out, int M)
{
    __shared__ __align__(16) unsigned short smw[2][16384];   // 64 KB: two weight matrices
    const int t = threadIdx.x, lane = t & 63, wave = t >> 6;
    const int base = blockIdx.x * 256 + wave * 32;
    const int s = lane & 31, h8 = (lane >> 5) * 8;
    const int arow = base + s;
    const int rowc = (arow < M) ? arow : (M - 1);
    const int si = psrc[rowc], sj = pdst[rowc];

    // issue all X loads upfront (fp8, 8 B each; HBM latency hides under the staging)
    bf16x8 xi[8], xj[8];
    #pragma unroll
    for (int kt = 0; kt < 8; kt++)
        xi[kt] = frag_from_f8(X + (size_t)si * 128 + kt * 16 + h8);
    #pragma unroll
    for (int kt = 0; kt < 8; kt++)
        xj[kt] = frag_from_f8(X + (size_t)sj * 128 + kt * 16 + h8);

    stage_w512(smw[0], W1a, t);
    stage_w512(smw[1], W1b, t);
    __syncthreads();

    // ---- layer 1: acc1 = W1a^T xi + W1b^T xj ----
    f32x16 acc1[4];
    #pragma unroll
    for (int nt = 0; nt < 4; nt++)
        #pragma unroll
        for (int q = 0; q < 16; q++) acc1[nt][q] = 0.f;
    #pragma unroll
    for (int kt = 0; kt < 8; kt++) {
        #pragma unroll
        for (int nt = 0; nt < 4; nt++) {
            bf16x8 wa = wfrag_lds(smw[0], kt * 4 + nt, lane);
            acc1[nt] = __builtin_amdgcn_mfma_f32_32x32x16_bf16(wa, xi[kt], acc1[nt], 0, 0, 0);
            bf16x8 wb = wfrag_lds(smw[1], kt * 4 + nt, lane);
            acc1[nt] = __builtin_amdgcn_mfma_f32_32x32x16_bf16(wb, xj[kt], acc1[nt], 0, 0, 0);
        }
    }
    __syncthreads();

    stage_w512(smw[0], W2p, t);
    stage_w512(smw[1], W3p, t);
    __syncthreads();

    // ---- layer 2 ----
    f32x16 acc2[4];
    #pragma unroll
    for (int nt = 0; nt < 4; nt++)
        #pragma unroll
        for (int q = 0; q < 16; q++) acc2[nt][q] = 0.f;
    #pragma unroll
    for (int kt = 0; kt < 8; kt++) {
        float4 bva = *(const float4*)(b1 + kt * 16 + h8);
        float4 bvb = *(const float4*)(b1 + kt * 16 + h8 + 4);
        bf16x8 yh = trans32(acc1[kt >> 1], (kt & 1) * 8, bva, bvb);
        #pragma unroll
        for (int nt = 0; nt < 4; nt++) {
            bf16x8 whi = wfrag_lds(smw[0], kt * 4 + nt, lane);
            acc2[nt] = __builtin_amdgcn_mfma_f32_32x32x16_bf16(whi, yh, acc2[nt], 0, 0, 0);
        }
    }

    // ---- layer 3 (W3 already staged; no barrier) ----
    f32x16 acc3[4];
    #pragma unroll
    for (int nt = 0; nt < 4; nt++)
        #pragma unroll
        for (int q = 0; q < 16; q++) acc3[nt][q] = 0.f;
    #pragma unroll
    for (int kt = 0; kt < 8; kt++) {
        float4 bva = *(const float4*)(b2 + kt * 16 + h8);
        float4 bvb = *(const float4*)(b2 + kt * 16 + h8 + 4);
        bf16x8 yh = trans32(acc2[kt >> 1], (kt & 1) * 8, bva, bvb);
        #pragma unroll
        for (int nt = 0; nt < 4; nt++) {
            bf16x8 whi = wfrag_lds(smw[1], kt * 4 + nt, lane);
            acc3[nt] = __builtin_amdgcn_mfma_f32_32x32x16_bf16(whi, yh, acc3[nt], 0, 0, 0);
        }
    }

    // ---- final: out = relu( sum_c relu(y3[c]) * w4[c] + b4 ) ----
    float p = 0.f;
    #pragma unroll
    for (int nt = 0; nt < 4; nt++) {
        int c1 = 32 * nt + h8;
        int c2 = 32 * nt + 16 + h8;
        float4 b3a = *(const float4*)(b3 + c1);
        float4 b3b = *(const float4*)(b3 + c1 + 4);
        float4 b3c = *(const float4*)(b3 + c2);
        float4 b3d = *(const float4*)(b3 + c2 + 4);
        float4 w4a = *(const float4*)(w4 + c1);
        float4 w4b = *(const float4*)(w4 + c1 + 4);
        float4 w4c = *(const float4*)(w4 + c2);
        float4 w4d = *(const float4*)(w4 + c2 + 4);
        p += fmaxf(acc3[nt][0]  + b3a.x, 0.f) * w4a.x;
        p += fmaxf(acc3[nt][1]  + b3a.y, 0.f) * w4a.y;
        p += fmaxf(acc3[nt][2]  + b3a.z, 0.f) * w4a.z;
        p += fmaxf(acc3[nt][3]  + b3a.w, 0.f) * w4a.w;
        p += fmaxf(acc3[nt][4]  + b3b.x, 0.f) * w4b.x;
        p += fmaxf(acc3[nt][5]  + b3b.y, 0.f) * w4b.y;
        p += fmaxf(acc3[nt][6]  + b3b.z, 0.f) * w4b.z;
        p += fmaxf(acc3[nt][7]  + b3b.w, 0.f) * w4b.w;
        p += fmaxf(acc3[nt][8]  + b3c.x, 0.f) * w4c.x;
        p += fmaxf(acc3[nt][9]  + b3c.y, 0.f) * w4c.y;
        p += fmaxf(acc3[nt][10] + b3c.z, 0.f) * w4c.z;
        p += fmaxf(acc3[nt][11] + b3c.w, 0.f) * w4c.w;
        p += fmaxf(acc3[nt][12] + b3d.x, 0.f) * w4d.x;
        p += fmaxf(acc3[nt][13] + b3d.y, 0.f) * w4d.y;
        p += fmaxf(acc3[nt][14] + b3d.z, 0.f) * w4d.z;
        p += fmaxf(acc3[nt][15] + b3d.w, 0.f) * w4d.w;
    }
    p += __shfl_xor(p, 32, 64);
    if (lane < 32 && arow < M) out[arow] = fmaxf(p + b4p[0], 0.f);
}

extern "C" void kernel_launch(void* const* d_in, const int* in_sizes, int n_in,
                              void* d_out, int out_size, void* d_ws, size_t ws_size,
                              hipStream_t stream)
{
    const float* x   = (const float*)d_in[0];
    const int*   ei  = (const int*)d_in[2];
    const int*   pei = (const int*)d_in[3];
    const float* W1  = (const float*)d_in[4];
    const float* b1  = (const float*)d_in[5];
    const float* W2  = (const float*)d_in[6];
    const float* b2  = (const float*)d_in[7];
    // d_in[8..11] = edge_mlp weights: dead w.r.t. output, skipped
    const float* pW1 = (const float*)d_in[12];
    const float* pb1 = (const float*)d_in[13];
    const float* pW2 = (const float*)d_in[14];
    const float* pb2 = (const float*)d_in[15];
    const float* pW3 = (const float*)d_in[16];
    const float* pb3 = (const float*)d_in[17];
    const float* pW4 = (const float*)d_in[18];
    const float* pb4 = (const float*)d_in[19];

    const int N  = in_sizes[0] / 128;
    const int E  = in_sizes[2] / 2;
    const int EP = in_sizes[3] / 2;
    const int Npad = (N + 255) & ~255;

    float*          ws     = (float*)d_ws;
    float*          dinv   = ws;                                    // Npad floats
    unsigned char*  hpF8   = (unsigned char*)(ws + Npad);           // N*128 B (fp8 plane)
    unsigned short* bufB   = (unsigned short*)(hpF8 + (size_t)N * 128);  // N*128 u16 (bf16 plane)
    unsigned char*  bufC   = (unsigned char*)(bufB + (size_t)N * 128);   // N*128 B (fp8 plane)
    size_t ioff = (((size_t)(bufC + (size_t)N * 128)) + 255) & ~(size_t)255;
    int*   deg    = (int*)ioff;                                     // Npad
    int*   rowptr = deg + Npad;                                     // Npad
    int*   rank   = rowptr + Npad;                                  // E
    int*   csr    = rank + E;                                       // E
    int*   bsum   = csr + E;                                        // 512
    size_t wpOff = ((size_t)(bsum + 512) + 15) & ~(size_t)15;
    unsigned short* wp = (unsigned short*)wpOff;                    // 6 x 16384 u16
    unsigned short* W1p  = wp;
    unsigned short* W2p  = wp + 16384;
    unsigned short* P1Ap = wp + 2 * 16384;
    unsigned short* P1Bp = wp + 3 * 16384;
    unsigned short* P2p  = wp + 4 * 16384;
    unsigned short* P3p  = wp + 5 * 16384;
    float* out = (float*)d_out;

    const int* esrc = ei;
    const int* edst = ei + E;
    const int* psrc = pei;
    const int* pdst = pei + EP;

    const int nb = (N + 255) / 256;
    const int gN = (N + 255) / 256;
    const int gE = (E + 255) / 256;
    const int gT = (N + 127) / 128;
    const int gP = (EP + 255) / 256;    // 256 samples per block (8 waves x 32)
    const int gG = (N + 15) / 16;

    // ---- CSR build + dinv (atomic-free placement via rank) ----
    zero1_k<<<gN, 256, 0, stream>>>(deg, N);
    hist_k<<<gE, 256, 0, stream>>>(edst, deg, rank, E);
    scan1_k<<<nb, 256, 0, stream>>>(deg, rowptr, bsum, dinv, N);
    scan2_k<<<1, 512, 0, stream>>>(bsum, nb);
    scan3_k<<<gN, 256, 0, stream>>>(rowptr, bsum, N);
    place_k<<<gE, 256, 0, stream>>>(esrc, edst, rowptr, rank, csr, E);

    // ---- weight prep (bf16, dual fragment format) ----
    wprep6_k<<<dim3(64, 6), 256, 0, stream>>>(W1, W2, pW1, pW1 + 128 * 128, pW2, pW3, wp);

    // ---- layer 0: hp1 = dinv ⊙ (x@W1) [fp8]; x1r = relu(agg + b1) [bf16] ----
    rowgemm_k<0><<<gT, 512, 0, stream>>>(x, W1p, dinv, hpF8, N);
    gather4_k<0><<<gG, 256, 0, stream>>>(hpF8, dinv, rowptr, deg, csr, b1, bufB, N);

    // ---- layer 1: hp2 = dinv ⊙ (x1r@W2) [fp8]; x2r = relu(agg + b2) [fp8] ----
    rowgemm_k<1><<<gT, 512, 0, stream>>>(bufB, W2p, dinv, hpF8, N);
    gather4_k<1><<<gG, 256, 0, stream>>>(hpF8, dinv, rowptr, deg, csr, b2, bufC, N);

    // ---- fused predict MLP (fp8 X, bf16 compute, 8 waves, 2-matrix LDS staging) ----
    mlp_k<<<gP, 512, 0, stream>>>(bufC, psrc, pdst, P1Ap, P1Bp, pb1, P2p, pb2, P3p, pb3,
                                  pW4, pb4, out, EP);
}